// Round 7
// baseline (3940.756 us; speedup 1.0000x reference)
//
#include <hip/hip_runtime.h>
#include <hip/hip_bf16.h>

#define BB 4
#define MM 8192
#define SS1 2048
#define SS2 512

using ull = unsigned long long;

// ---------------- DPP helpers ----------
template <int CTRL>
__device__ __forceinline__ void dpp_max_step(ull& k) {
  unsigned lo = (unsigned)k, hi = (unsigned)(k >> 32);
  unsigned plo = (unsigned)__builtin_amdgcn_update_dpp(0, (int)lo, CTRL, 0xF, 0xF, true);
  unsigned phi = (unsigned)__builtin_amdgcn_update_dpp(0, (int)hi, CTRL, 0xF, 0xF, true);
  ull pk = ((ull)phi << 32) | plo;
  if (pk > k) k = pk;
}

// full-wave max, result in lane 63
__device__ __forceinline__ void wave_max_u64(ull& k) {
  dpp_max_step<0x111>(k);  // row_shr:1
  dpp_max_step<0x112>(k);  // row_shr:2
  dpp_max_step<0x114>(k);  // row_shr:4
  dpp_max_step<0x118>(k);  // row_shr:8
  dpp_max_step<0x142>(k);  // row_bcast:15
  dpp_max_step<0x143>(k);  // row_bcast:31 -> lane63 = wave max
}

// 8-lane max (entries in lanes 0..7), result in lane 7: 3 dependent steps
__device__ __forceinline__ void row8_max_u64(ull& k) {
  dpp_max_step<0x111>(k);
  dpp_max_step<0x112>(k);
  dpp_max_step<0x114>(k);
}

// ---------------- farthest point sampling core (multi-wave, 8 waves) ----------------
// Exact f32 numpy semantics: contract off, x*x then +y*y then +z*z; argmax
// ties -> lowest index via key (d2_bits<<32)|~idx. Register-resident points,
// one wave_max + one barrier per iter, centers staged in LDS cbuf.
// R18 tail cut: row16+64-bit shfl (2 ds_bpermute) replaced by row8 (3 DPP) +
// readlane of the LOW WORD only (index is all we need; coords come from the
// sp[widx] broadcast read). ~150-250cy off the serial per-iter tail.
template <int MP, int NSEL, int THREADS>
__device__ __forceinline__ void fps_core(const float* __restrict__ p,
                                         float* __restrict__ c_out,
                                         char* smem) {
  constexpr int E = MP / THREADS;
  constexpr int W = THREADS / 64;
  static_assert(W == 8, "row8 tail assumes exactly 8 waves");
  static_assert(MP % THREADS == 0, "geometry");
  float4* sp = (float4*)smem;                                    // 16*MP
  float* cbuf = (float*)(smem + sizeof(float4) * MP);            // 12*NSEL
  ull* kb = (ull*)(smem + sizeof(float4) * MP + sizeof(float) * NSEL * 3);  // 2*W*8
  int t = threadIdx.x;
  int lane = t & 63, wv = t >> 6;
  for (int i = t; i < MP; i += THREADS)
    sp[i] = make_float4(p[i * 3 + 0], p[i * 3 + 1], p[i * 3 + 2], 0.f);
  __syncthreads();
  // register-resident copy of this thread's E points (strided mapping) + dd
  float mx[E], my[E], mz[E], dd[E];
  #pragma unroll
  for (int e = 0; e < E; ++e) {
    float4 q = sp[t + e * THREADS];  // conflict-free ds_read_b128, once
    mx[e] = q.x; my[e] = q.y; mz[e] = q.z;
    dd[e] = INFINITY;
  }
  float4 c0 = sp[0];
  float cx = c0.x, cy = c0.y, cz = c0.z;
  if (t == 0) { cbuf[0] = cx; cbuf[1] = cy; cbuf[2] = cz; }
  int par = 0;
  for (int it = 1; it < NSEL; ++it) {
    float bd = -1.0f;
    int be = 0;
    {
      #pragma clang fp contract(off)
      #pragma unroll
      for (int e = 0; e < E; ++e) {
        float dx = mx[e] - cx, dy = my[e] - cy, dz = mz[e] - cz;
        float nd = dx * dx;
        nd += dy * dy;
        nd += dz * dz;
        float d = fminf(dd[e], nd);
        dd[e] = d;
        if (d > bd) { bd = d; be = e; }  // strict > keeps lowest e (lowest idx)
      }
    }
    int bidx = t + be * THREADS;  // idx monotone in e -> in-thread ties exact
    ull k = ((ull)__float_as_uint(bd) << 32) | (unsigned)(~bidx);
    wave_max_u64(k);
    if (lane == 63) kb[par * W + wv] = k;
    __syncthreads();
    ull v = 0;
    if (lane < W) v = kb[par * W + lane];  // one predicated ds_read_b64 per wave
    row8_max_u64(v);                       // lane7 = block max (W==8)
    unsigned glo = __builtin_amdgcn_readlane((unsigned)v, 7);  // low word: ~bidx
    int widx = (int)(~glo) & (MP - 1);  // mask: replay-safe no-op
    float4 cw = sp[widx];  // uniform address -> LDS broadcast
    cx = cw.x; cy = cw.y; cz = cw.z;
    if (t == 0) {
      cbuf[it * 3 + 0] = cx;
      cbuf[it * 3 + 1] = cy;
      cbuf[it * 3 + 2] = cz;
    }
    par ^= 1;
  }
  __syncthreads();
  for (int i = t; i < NSEL * 3; i += THREADS) c_out[i] = cbuf[i];
}

// ---------------- single-wave FPS core (R18, for small MP) ----------------
// One wave owns the whole batch: NO barriers, NO cross-wave reduce, NO kb/shfl.
// Tail per iter = wave_max + readlane + one LDS broadcast read. Centers are
// stored DIRECTLY to global: with no barrier in the loop there is no forced
// vmcnt(0) drain (R5 showed stores only cost when a barrier drains them).
// Exactness: same key scheme; element mapping lane + e*64 maps keys to true
// original indices; in-thread spine keeps lowest e = lowest idx for ties.
template <int MP, int NSEL>
__device__ __forceinline__ void fps_core_1w(const float* __restrict__ p,
                                            float* __restrict__ c_out,
                                            char* smem) {
  constexpr int E = MP / 64;
  float4* sp = (float4*)smem;
  int lane = threadIdx.x & 63;
  for (int i = lane; i < MP; i += 64)
    sp[i] = make_float4(p[i * 3 + 0], p[i * 3 + 1], p[i * 3 + 2], 0.f);
  asm volatile("s_waitcnt lgkmcnt(0)" ::: "memory");  // same-wave staging visible
  float mx[E], my[E], mz[E], dd[E];
  #pragma unroll
  for (int e = 0; e < E; ++e) {
    float4 q = sp[lane + e * 64];
    mx[e] = q.x; my[e] = q.y; mz[e] = q.z;
    dd[e] = INFINITY;
  }
  float4 c0 = sp[0];
  float cx = c0.x, cy = c0.y, cz = c0.z;
  if (lane == 0) { c_out[0] = cx; c_out[1] = cy; c_out[2] = cz; }
  for (int it = 1; it < NSEL; ++it) {
    float bd = -1.0f;
    int be = 0;
    {
      #pragma clang fp contract(off)
      #pragma unroll
      for (int e = 0; e < E; ++e) {
        float dx = mx[e] - cx, dy = my[e] - cy, dz = mz[e] - cz;
        float nd = dx * dx;
        nd += dy * dy;
        nd += dz * dz;
        float d = fminf(dd[e], nd);
        dd[e] = d;
        if (d > bd) { bd = d; be = e; }  // strict > keeps lowest e (lowest idx)
      }
    }
    int bidx = lane + be * 64;
    ull k = ((ull)__float_as_uint(bd) << 32) | (unsigned)(~bidx);
    wave_max_u64(k);  // lane63 = wave (= batch) max
    unsigned glo = __builtin_amdgcn_readlane((unsigned)k, 63);
    int widx = (int)(~glo) & (MP - 1);
    float4 cw = sp[widx];  // uniform address -> LDS broadcast
    cx = cw.x; cy = cw.y; cz = cw.z;
    if (lane == 0) {  // fire-and-forget stores; no barrier ever drains them
      c_out[it * 3 + 0] = cx;
      c_out[it * 3 + 1] = cy;
      c_out[it * 3 + 2] = cz;
    }
  }
}

// ---------------- ball query core: 64 nearest with d2 <= R2, ties by lower index ----------------
// One wave per center, NW waves per block. Output indices i16 (-1..8191 lossless).
template <int MP, int NW>
__device__ __forceinline__ void nbr_core(const float* __restrict__ pts,
                                         const float* __restrict__ cen, int S,
                                         float R2, short* __restrict__ nbr,
                                         ull* buf, int blk) {
  constexpr int CAP = 1024;
  int t = threadIdx.x;
  int wv = t >> 6, lane = t & 63;
  int gw = blk * NW + wv;
  int b = gw / S, s = gw % S;
  const float* p = pts + (size_t)b * MP * 3;
  const float* c = cen + ((size_t)b * S + s) * 3;
  float cx = c[0], cy = c[1], cz = c[2];
  ull* bw = buf + (size_t)wv * CAP;
  int cnt = 0;
  {
    #pragma clang fp contract(off)
    for (int i0 = 0; i0 < MP; i0 += 64) {
      int i = i0 + lane;
      float dx = p[i * 3 + 0] - cx;
      float dy = p[i * 3 + 1] - cy;
      float dz = p[i * 3 + 2] - cz;
      float d2 = dx * dx;
      d2 += dy * dy;
      d2 += dz * dz;
      bool in = (d2 <= R2);
      ull mask = __ballot(in);
      if (in) {
        int off = __popcll(mask & ((1ull << lane) - 1ull));
        int pos = cnt + off;
        if (pos < CAP)
          bw[pos] = ((ull)__float_as_uint(d2) << 32) | (unsigned)i;
      }
      cnt += __popcll(mask);
    }
  }
  if (cnt > CAP) cnt = CAP;
  __syncthreads();  // uniform within this path; ensures LDS writes visible
  int out = -1;
  if (cnt <= 64) {
    if (lane < cnt) out = (int)(unsigned)bw[lane];
  } else {
    for (int r = 0; r < 64; ++r) {
      ull mk = ~0ull;
      int mj = -1;
      for (int j = lane; j < cnt; j += 64) {
        ull v = bw[j];
        if (v < mk) { mk = v; mj = j; }
      }
      ull kc = ~mk;
      wave_max_u64(kc);
      ull g = ~__shfl(kc, 63, 64);
      if (mk == g && mj >= 0) bw[mj] = ~0ull;  // unique keys -> exactly one owner
      asm volatile("s_waitcnt lgkmcnt(0)" ::: "memory");
      if (lane == r) out = (int)(unsigned)g;
    }
  }
  nbr[((size_t)b * S + s) * 64 + lane] = (short)out;
}

// ---------------- K_A: fps1 (blocks 0..3) U local MLP (blocks 4..4+BB*MM/8) ----------------
// local branch: pos -> 64 -> 64 -> 128 (tanh each), 8 points per 512-thread block.
__global__ __launch_bounds__(512) void k_fps1_local(
    const float* __restrict__ pos, float* __restrict__ c1,
    const float* __restrict__ w0, const float* __restrict__ b0,
    const float* __restrict__ w1, const float* __restrict__ b1,
    const float* __restrict__ w2, const float* __restrict__ b2,
    float* __restrict__ out) {
  __shared__ __align__(16) char smem[16 * MM + 12 * SS1 + 128];  // 155,776 B
  if (blockIdx.x < BB) {
    int b = blockIdx.x;
    fps_core<MM, SS1, 512>(pos + (size_t)b * MM * 3, c1 + (size_t)b * SS1 * 3, smem);
  } else {
    float* p  = (float*)smem;           // [8][3]
    float* h0 = (float*)smem + 32;      // [8][64]
    float* h1 = (float*)smem + 32 + 512;// [8][64]
    int t = threadIdx.x;
    size_t pid0 = (size_t)(blockIdx.x - BB) * 8;
    if (t < 24) {
      int pp = t / 3, j = t % 3;
      p[pp * 3 + j] = pos[(pid0 + pp) * 3 + j];
    }
    __syncthreads();
    {
      int pp = t >> 6, c = t & 63;
      float acc = b0[c];
      #pragma unroll
      for (int j = 0; j < 3; ++j) acc += p[pp * 3 + j] * w0[j * 64 + c];
      h0[pp * 64 + c] = tanhf(acc);
    }
    __syncthreads();
    {
      int pp = t >> 6, c = t & 63;
      float acc = b1[c];
      #pragma unroll
      for (int j = 0; j < 64; ++j) acc += h0[pp * 64 + j] * w1[j * 64 + c];
      h1[pp * 64 + c] = tanhf(acc);
    }
    __syncthreads();
    #pragma unroll
    for (int r = 0; r < 2; ++r) {
      int o = t + 512 * r;
      int pp = o >> 7, c = o & 127;
      float acc = b2[c];
      #pragma unroll
      for (int j = 0; j < 64; ++j) acc += h1[pp * 64 + j] * w2[j * 128 + c];
      out[(pid0 + pp) * 128 + c] = tanhf(acc);
    }
  }
}

// standalone fps1 (fallback path when scratch aliases d_out: local must run LAST)
__global__ __launch_bounds__(512, 1) void fps1_kernel(const float* __restrict__ pts,
                                                      float* __restrict__ cen) {
  __shared__ __align__(16) char smem[16 * MM + 12 * SS1 + 128];
  fps_core<MM, SS1, 512>(pts + (size_t)blockIdx.x * MM * 3,
                         cen + (size_t)blockIdx.x * SS1 * 3, smem);
}

// standalone local MLP (fallback path), 8 pts per 512-thread block
__global__ __launch_bounds__(512) void local_mlp_kernel(
    const float* __restrict__ pos,
    const float* __restrict__ w0, const float* __restrict__ b0,
    const float* __restrict__ w1, const float* __restrict__ b1,
    const float* __restrict__ w2, const float* __restrict__ b2,
    float* __restrict__ out) {
  __shared__ float p[8][3];
  __shared__ float h0[8][64];
  __shared__ float h1[8][64];
  int t = threadIdx.x;
  size_t pid0 = (size_t)blockIdx.x * 8;
  if (t < 24) {
    int pp = t / 3, j = t % 3;
    p[pp][j] = pos[(pid0 + pp) * 3 + j];
  }
  __syncthreads();
  {
    int pp = t >> 6, c = t & 63;
    float acc = b0[c];
    #pragma unroll
    for (int j = 0; j < 3; ++j) acc += p[pp][j] * w0[j * 64 + c];
    h0[pp][c] = tanhf(acc);
  }
  __syncthreads();
  {
    int pp = t >> 6, c = t & 63;
    float acc = b1[c];
    #pragma unroll
    for (int j = 0; j < 64; ++j) acc += h0[pp][j] * w1[j * 64 + c];
    h1[pp][c] = tanhf(acc);
  }
  __syncthreads();
  #pragma unroll
  for (int r = 0; r < 2; ++r) {
    int o = t + 512 * r;
    int pp = o >> 7, c = o & 127;
    float acc = b2[c];
    #pragma unroll
    for (int j = 0; j < 64; ++j) acc += h1[pp][j] * w2[j * 128 + c];
    out[(pid0 + pp) * 128 + c] = tanhf(acc);
  }
}

// ---------------- K_B: fps2 single-wave (blocks 0..3) U nbr1 (blocks 4..) ----------------
__global__ __launch_bounds__(512) void k_fps2_nbr1(
    const float* __restrict__ pos, const float* __restrict__ c1,
    float* __restrict__ c2, short* __restrict__ nbr1) {
  __shared__ __align__(16) char smem[8 * 1024 * 8];  // 64 KB (nbr) >= 32 KB (fps2 sp)
  if (blockIdx.x < BB) {
    if (threadIdx.x >= 64) return;  // single-wave path: NO barriers below
    int b = blockIdx.x;
    fps_core_1w<SS1, SS2>(c1 + (size_t)b * SS1 * 3, c2 + (size_t)b * SS2 * 3, smem);
  } else {
    nbr_core<MM, 8>(pos, c1, SS1, 0.04f, nbr1, (ull*)smem, blockIdx.x - BB);
  }
}

// ---------------- K_C: group1 (blocks 0..BB*SS1) U nbr2 (tail blocks) ----------------
// SA1 grouped MLP: feats[64][9] -> 64 -> 128, masked PRE-ACT max over K;
// layer2 register-tiled 8k x 4ch; tanh/bias deferred past the masked max (exact).
__global__ __launch_bounds__(256, 4) void k_group1_nbr2(
    const float* __restrict__ pos, const float* __restrict__ x,
    const float* __restrict__ c1, const short* __restrict__ nbr,
    const float* __restrict__ w0, const float* __restrict__ b0,
    const float* __restrict__ w1, const float* __restrict__ b1,
    float* __restrict__ h1out,
    const float* __restrict__ c2, short* __restrict__ nbr2out) {
  __shared__ __align__(16) char smem[32768];  // nbr2 32KB >= group1 ~24.9KB
  if (blockIdx.x >= BB * SS1) {
    nbr_core<SS1, 4>(c1, c2, SS2, 0.16f, nbr2out, (ull*)smem, blockIdx.x - BB * SS1);
    return;
  }
  float (*feats)[12] = (float(*)[12])smem;                    // 3072 B
  float (*hbuf)[68]  = (float(*)[68])(smem + 3072);           // 17408 B
  float (*Mred)[128] = (float(*)[128])(smem + 3072 + 17408);  // 4096 B
  int* nb            = (int*)(smem + 3072 + 17408 + 4096);    // 256 B
  float* cc          = (float*)(smem + 3072 + 17408 + 4096 + 256);  // 12 B
  int t = threadIdx.x;
  int bs = blockIdx.x;  // b*S1 + s
  int b = bs >> 11;
  if (t < 64) nb[t] = (int)nbr[(size_t)bs * 64 + t];
  if (t < 3) cc[t] = c1[(size_t)bs * 3 + t];
  __syncthreads();
  if (t < 64) {
    int n = nb[t];
    int ni = ((unsigned)n < (unsigned)MM) ? n : 0;  // clamp: replay-safe
    const float* pp = pos + ((size_t)b * MM + ni) * 3;
    const float* xx = x + ((size_t)b * MM + ni) * 3;
    float p0 = pp[0], p1 = pp[1], p2 = pp[2];
    feats[t][0] = p0; feats[t][1] = p1; feats[t][2] = p2;
    feats[t][3] = xx[0]; feats[t][4] = xx[1]; feats[t][5] = xx[2];
    feats[t][6] = p0 - cc[0]; feats[t][7] = p1 - cc[1]; feats[t][8] = p2 - cc[2];
  }
  __syncthreads();
  // layer1: 9 -> 64; thread (k = t>>2, q = t&3) computes 16 channels
  {
    int k = t >> 2, q = t & 3;
    float acc[16];
    #pragma unroll
    for (int i = 0; i < 16; ++i) acc[i] = b0[q * 16 + i];
    #pragma unroll
    for (int j = 0; j < 9; ++j) {
      float f = feats[k][j];
      const float4* wr = (const float4*)(w0 + j * 64 + q * 16);
      #pragma unroll
      for (int i = 0; i < 4; ++i) {
        float4 wvv = wr[i];
        acc[4 * i + 0] += f * wvv.x;
        acc[4 * i + 1] += f * wvv.y;
        acc[4 * i + 2] += f * wvv.z;
        acc[4 * i + 3] += f * wvv.w;
      }
    }
    #pragma unroll
    for (int i = 0; i < 16; ++i) hbuf[k][q * 16 + i] = tanhf(acc[i]);
  }
  __syncthreads();
  // layer2: hidden[64][64] x W1[64][128], masked PRE-ACT max over k
  {
    int kt = t >> 5;  // 0..7
    int ct = t & 31;  // 0..31
    float acc[8][4];
    #pragma unroll
    for (int a = 0; a < 8; ++a)
      #pragma unroll
      for (int ci = 0; ci < 4; ++ci) acc[a][ci] = 0.f;
    const float* wbase = w1 + ct * 4;
    for (int j = 0; j < 64; j += 2) {
      float2 fv[8];
      #pragma unroll
      for (int kk = 0; kk < 8; ++kk)
        fv[kk] = *(const float2*)&hbuf[kt * 8 + kk][j];
      float wja[4], wjb[4];
      *(float4*)&wja[0] = *(const float4*)(wbase + (size_t)j * 128);
      *(float4*)&wjb[0] = *(const float4*)(wbase + (size_t)(j + 1) * 128);
      #pragma unroll
      for (int kk = 0; kk < 8; ++kk)
        #pragma unroll
        for (int ci = 0; ci < 4; ++ci) {
          acc[kk][ci] += fv[kk].x * wja[ci];
          acc[kk][ci] += fv[kk].y * wjb[ci];
        }
    }
    float m[4];
    #pragma unroll
    for (int ci = 0; ci < 4; ++ci) m[ci] = -INFINITY;
    #pragma unroll
    for (int kk = 0; kk < 8; ++kk) {
      if (nb[kt * 8 + kk] >= 0) {
        #pragma unroll
        for (int ci = 0; ci < 4; ++ci) m[ci] = fmaxf(m[ci], acc[kk][ci]);
      }
    }
    #pragma unroll
    for (int ci = 0; ci < 4; ++ci) Mred[kt][ct * 4 + ci] = m[ci];
  }
  __syncthreads();
  if (t < 128) {
    float mxv = Mred[0][t];
    #pragma unroll
    for (int r = 1; r < 8; ++r) mxv = fmaxf(mxv, Mred[r][t]);
    h1out[(size_t)bs * 128 + t] = tanhf(mxv + b1[t]);  // bias+tanh after max: exact
  }
}

// ---------------- SA2 grouped MLP: feats[64][131] -> 128 -> 256, masked max over K ----------------
__global__ __launch_bounds__(256, 4) void group2_kernel(
    const float* __restrict__ h1, const float* __restrict__ c1,
    const float* __restrict__ c2, const short* __restrict__ nbr,
    const float* __restrict__ w0, const float* __restrict__ b0,
    const float* __restrict__ w1, const float* __restrict__ b1,
    float* __restrict__ h2out) {
  __shared__ float fb[64][132];  // feats (131) then reused as hidden (128)
  __shared__ float Mred[8][256];
  __shared__ int nb[64];
  __shared__ float cc[3];
  int t = threadIdx.x;
  int bs = blockIdx.x;  // b*S2 + s
  int b = bs >> 9;
  if (t < 64) nb[t] = (int)nbr[(size_t)bs * 64 + t];
  if (t < 3) cc[t] = c2[(size_t)bs * 3 + t];
  __syncthreads();
  {
    int k = t >> 2, q = t & 3;
    int n = nb[k];
    int ni = ((unsigned)n < (unsigned)SS1) ? n : 0;  // clamp: replay-safe
    const float* hrow = h1 + ((size_t)b * SS1 + ni) * 128;
    #pragma unroll
    for (int i = 0; i < 32; ++i) fb[k][q * 32 + i] = hrow[q * 32 + i];
    if (q == 0) {
      const float* pr = c1 + ((size_t)b * SS1 + ni) * 3;
      fb[k][128] = pr[0] - cc[0];
      fb[k][129] = pr[1] - cc[1];
      fb[k][130] = pr[2] - cc[2];
    }
  }
  __syncthreads();
  float acc1[32];
  {
    int k = t >> 2, q = t & 3;
    #pragma unroll
    for (int i = 0; i < 32; ++i) acc1[i] = b0[q * 32 + i];
    for (int j = 0; j < 131; ++j) {
      float f = fb[k][j];
      const float4* wr = (const float4*)(w0 + (size_t)j * 128 + q * 32);
      #pragma unroll
      for (int i = 0; i < 8; ++i) {
        float4 wvv = wr[i];
        acc1[4 * i + 0] += f * wvv.x;
        acc1[4 * i + 1] += f * wvv.y;
        acc1[4 * i + 2] += f * wvv.z;
        acc1[4 * i + 3] += f * wvv.w;
      }
    }
  }
  __syncthreads();
  {
    int k = t >> 2, q = t & 3;
    #pragma unroll
    for (int i = 0; i < 32; ++i) fb[k][q * 32 + i] = tanhf(acc1[i]);
  }
  __syncthreads();
  {
    int kt = t >> 5;  // 0..7
    int ct = t & 31;  // 0..31
    float acc[8][8];
    #pragma unroll
    for (int a = 0; a < 8; ++a)
      #pragma unroll
      for (int c2i = 0; c2i < 8; ++c2i) acc[a][c2i] = 0.f;
    const float* wbase = w1 + ct * 8;
    for (int j = 0; j < 128; j += 2) {
      float2 fv[8];
      #pragma unroll
      for (int kk = 0; kk < 8; ++kk)
        fv[kk] = *(const float2*)&fb[kt * 8 + kk][j];
      float wja[8], wjb[8];
      const float4* wp0 = (const float4*)(wbase + (size_t)j * 256);
      const float4* wp1 = (const float4*)(wbase + (size_t)(j + 1) * 256);
      *(float4*)&wja[0] = wp0[0];
      *(float4*)&wja[4] = wp0[1];
      *(float4*)&wjb[0] = wp1[0];
      *(float4*)&wjb[4] = wp1[1];
      #pragma unroll
      for (int kk = 0; kk < 8; ++kk)
        #pragma unroll
        for (int ci = 0; ci < 8; ++ci) {
          acc[kk][ci] += fv[kk].x * wja[ci];
          acc[kk][ci] += fv[kk].y * wjb[ci];
        }
    }
    float m[8];
    #pragma unroll
    for (int ci = 0; ci < 8; ++ci) m[ci] = -INFINITY;
    #pragma unroll
    for (int kk = 0; kk < 8; ++kk) {
      if (nb[kt * 8 + kk] >= 0) {
        #pragma unroll
        for (int ci = 0; ci < 8; ++ci) m[ci] = fmaxf(m[ci], acc[kk][ci]);
      }
    }
    #pragma unroll
    for (int ci = 0; ci < 8; ++ci) Mred[kt][ct * 8 + ci] = m[ci];
  }
  __syncthreads();
  if (t < 256) {
    float mxv = Mred[0][t];
    #pragma unroll
    for (int r = 1; r < 8; ++r) mxv = fmaxf(mxv, Mred[r][t]);
    h2out[(size_t)bs * 256 + t] = tanhf(mxv + b1[t]);  // bias+tanh after max: exact
  }
}

// ---------------- global max over centers ----------------
__global__ __launch_bounds__(256) void gmax_kernel(const float* __restrict__ h2,
                                                   float* __restrict__ out) {
  int b = blockIdx.x, c = threadIdx.x;
  float mx = -INFINITY;
  for (int s = 0; s < SS2; ++s)
    mx = fmaxf(mx, h2[((size_t)b * SS2 + s) * 256 + c]);
  out[(size_t)BB * MM * 128 + b * 256 + c] = mx;
}

extern "C" void kernel_launch(void* const* d_in, const int* in_sizes, int n_in,
                              void* d_out, int out_size, void* d_ws, size_t ws_size,
                              hipStream_t stream) {
  // Reference is pure float32: all inputs AND the output buffer are f32.
  const float* x    = (const float*)d_in[0];
  const float* pos  = (const float*)d_in[1];
  const float* lw0  = (const float*)d_in[2];
  const float* lb0  = (const float*)d_in[3];
  const float* lw1  = (const float*)d_in[4];
  const float* lb1  = (const float*)d_in[5];
  const float* lw2  = (const float*)d_in[6];
  const float* lb2  = (const float*)d_in[7];
  const float* g1w0 = (const float*)d_in[8];
  const float* g1b0 = (const float*)d_in[9];
  const float* g1w1 = (const float*)d_in[10];
  const float* g1b1 = (const float*)d_in[11];
  const float* g2w0 = (const float*)d_in[12];
  const float* g2b0 = (const float*)d_in[13];
  const float* g2w1 = (const float*)d_in[14];
  const float* g2b1 = (const float*)d_in[15];
  float* out = (float*)d_out;

  // Scratch (7.73 MB with i16 neighbor indices): prefer d_ws; fall back to
  // the local-output region of d_out (16.8 MB). With d_ws, local MLP can be
  // fused into the fps1 launch (it writes d_out directly); without, local
  // must run LAST since scratch aliases its output region.
  const size_t NEED = 7725056;
  bool has_ws = (ws_size >= NEED);
  char* sc = has_ws ? (char*)d_ws : (char*)d_out;
  float* h1   = (float*)(sc + 0);        // 4*2048*128 f32 = 4,194,304 B
  float* h2   = (float*)(sc + 4194304);  // 4*512*256 f32  = 2,097,152 B
  float* c1   = (float*)(sc + 6291456);  // 4*2048*3 f32   =    98,304 B
  float* c2   = (float*)(sc + 6389760);  // 4*512*3 f32    =    24,576 B
  short* nbr1 = (short*)(sc + 6414336);  // 4*2048*64 i16  = 1,048,576 B
  short* nbr2 = (short*)(sc + 7462912);  // 4*512*64 i16   =   262,144 B (end 7,725,056)

  if (has_ws) {
    // fused schedule: fps1 hides local_mlp; fps2 hides nbr1; group1 hides nbr2
    k_fps1_local<<<BB + BB * MM / 8, 512, 0, stream>>>(
        pos, c1, lw0, lb0, lw1, lb1, lw2, lb2, out);
  } else {
    fps1_kernel<<<BB, 512, 0, stream>>>(pos, c1);
  }
  k_fps2_nbr1<<<BB + BB * SS1 / 8, 512, 0, stream>>>(pos, c1, c2, nbr1);
  k_group1_nbr2<<<BB * SS1 + BB * SS2 / 4, 256, 0, stream>>>(
      pos, x, c1, nbr1, g1w0, g1b0, g1w1, g1b1, h1, c2, nbr2);
  group2_kernel<<<BB * SS2, 256, 0, stream>>>(h1, c1, c2, nbr2, g2w0, g2b0, g2w1, g2b1, h2);
  gmax_kernel<<<BB, 256, 0, stream>>>(h2, out);
  if (!has_ws) {
    local_mlp_kernel<<<BB * MM / 8, 512, 0, stream>>>(pos, lw0, lb0, lw1, lb1, lw2, lb2, out);
  }
}

// Round 8
// 3891.494 us; speedup vs baseline: 1.0127x; 1.0127x over previous
//
#include <hip/hip_runtime.h>
#include <hip/hip_bf16.h>

#define BB 4
#define MM 8192
#define SS1 2048
#define SS2 512

using ull = unsigned long long;

// ---------------- DPP helpers ----------
template <int CTRL>
__device__ __forceinline__ void dpp_max_step(ull& k) {
  unsigned lo = (unsigned)k, hi = (unsigned)(k >> 32);
  unsigned plo = (unsigned)__builtin_amdgcn_update_dpp(0, (int)lo, CTRL, 0xF, 0xF, true);
  unsigned phi = (unsigned)__builtin_amdgcn_update_dpp(0, (int)hi, CTRL, 0xF, 0xF, true);
  ull pk = ((ull)phi << 32) | plo;
  if (pk > k) k = pk;
}

// full-wave max, result in lane 63
__device__ __forceinline__ void wave_max_u64(ull& k) {
  dpp_max_step<0x111>(k);  // row_shr:1
  dpp_max_step<0x112>(k);  // row_shr:2
  dpp_max_step<0x114>(k);  // row_shr:4
  dpp_max_step<0x118>(k);  // row_shr:8
  dpp_max_step<0x142>(k);  // row_bcast:15
  dpp_max_step<0x143>(k);  // row_bcast:31 -> lane63 = wave max
}

// ---------------- farthest point sampling core (8 waves) ----------------
// Exact f32 numpy semantics: contract off, x*x then +y*y then +z*z; argmax
// ties -> lowest index via key (d2_bits<<32)|~idx. Register-resident points,
// one barrier per iter, centers staged in LDS cbuf.
// R19 tail: cross-wave reduce via LDS ds_max_u64 into gk[4] rotating slots
// (replaces kb read + row8 DPP + readlane ~340cy with one uniform ds_read_b64
// ~120cy). Slot rotation is race-free: in any barrier window, reads hit slot
// it&3, atomics hit (it+1)&3, resets hit (it+3)&3 -- all distinct mod 4.
// u64 atomicMax is order-independent; keys/tie-breaks identical to R13-R18.
template <int MP, int NSEL, int THREADS>
__device__ __forceinline__ void fps_core(const float* __restrict__ p,
                                         float* __restrict__ c_out,
                                         char* smem) {
  constexpr int E = MP / THREADS;
  static_assert(MP % THREADS == 0, "geometry");
  float4* sp = (float4*)smem;                                    // 16*MP
  float* cbuf = (float*)(smem + sizeof(float4) * MP);            // 12*NSEL
  ull* gk = (ull*)(smem + sizeof(float4) * MP + sizeof(float) * NSEL * 3);  // gk[4]
  int t = threadIdx.x;
  int lane = t & 63;
  for (int i = t; i < MP; i += THREADS)
    sp[i] = make_float4(p[i * 3 + 0], p[i * 3 + 1], p[i * 3 + 2], 0.f);
  if (t == 0) { gk[0] = 0; gk[1] = 0; gk[2] = 0; gk[3] = 0; }
  __syncthreads();
  // register-resident copy of this thread's E points (strided mapping) + dd
  float mx[E], my[E], mz[E], dd[E];
  #pragma unroll
  for (int e = 0; e < E; ++e) {
    float4 q = sp[t + e * THREADS];  // conflict-free ds_read_b128, once
    mx[e] = q.x; my[e] = q.y; mz[e] = q.z;
    dd[e] = INFINITY;
  }
  float4 c0 = sp[0];
  float cx = c0.x, cy = c0.y, cz = c0.z;
  if (t == 0) { cbuf[0] = cx; cbuf[1] = cy; cbuf[2] = cz; }
  int slot = 1;  // it & 3
  for (int it = 1; it < NSEL; ++it) {
    float bd = -1.0f;
    int be = 0;
    {
      #pragma clang fp contract(off)
      #pragma unroll
      for (int e = 0; e < E; ++e) {
        float dx = mx[e] - cx, dy = my[e] - cy, dz = mz[e] - cz;
        float nd = dx * dx;
        nd += dy * dy;
        nd += dz * dz;
        float d = fminf(dd[e], nd);
        dd[e] = d;
        if (d > bd) { bd = d; be = e; }  // strict > keeps lowest e (lowest idx)
      }
    }
    int bidx = t + be * THREADS;  // idx monotone in e -> in-thread ties exact
    ull k = ((ull)__float_as_uint(bd) << 32) | (unsigned)(~bidx);
    wave_max_u64(k);
    if (lane == 63) atomicMax(&gk[slot], k);  // one ds_max_u64 per wave
    int rst = (slot + 2) & 3;
    if (t == 0) gk[rst] = 0;  // reset slot for it+2 (race-free, see header)
    __syncthreads();
    ull g = gk[slot];  // uniform address -> LDS broadcast
    int widx = (int)(~(unsigned)g) & (MP - 1);  // mask: replay-safe no-op
    float4 cw = sp[widx];  // uniform address -> LDS broadcast
    cx = cw.x; cy = cw.y; cz = cw.z;
    if (t == 0) {
      cbuf[it * 3 + 0] = cx;
      cbuf[it * 3 + 1] = cy;
      cbuf[it * 3 + 2] = cz;
    }
    slot = (slot + 1) & 3;
  }
  __syncthreads();
  for (int i = t; i < NSEL * 3; i += THREADS) c_out[i] = cbuf[i];
}

// ---------------- ball query core: 64 nearest with d2 <= R2, ties by lower index ----------------
// One wave per center, NW waves per block. Output indices i16 (-1..8191 lossless).
template <int MP, int NW>
__device__ __forceinline__ void nbr_core(const float* __restrict__ pts,
                                         const float* __restrict__ cen, int S,
                                         float R2, short* __restrict__ nbr,
                                         ull* buf, int blk) {
  constexpr int CAP = 1024;
  int t = threadIdx.x;
  int wv = t >> 6, lane = t & 63;
  int gw = blk * NW + wv;
  int b = gw / S, s = gw % S;
  const float* p = pts + (size_t)b * MP * 3;
  const float* c = cen + ((size_t)b * S + s) * 3;
  float cx = c[0], cy = c[1], cz = c[2];
  ull* bw = buf + (size_t)wv * CAP;
  int cnt = 0;
  {
    #pragma clang fp contract(off)
    for (int i0 = 0; i0 < MP; i0 += 64) {
      int i = i0 + lane;
      float dx = p[i * 3 + 0] - cx;
      float dy = p[i * 3 + 1] - cy;
      float dz = p[i * 3 + 2] - cz;
      float d2 = dx * dx;
      d2 += dy * dy;
      d2 += dz * dz;
      bool in = (d2 <= R2);
      ull mask = __ballot(in);
      if (in) {
        int off = __popcll(mask & ((1ull << lane) - 1ull));
        int pos = cnt + off;
        if (pos < CAP)
          bw[pos] = ((ull)__float_as_uint(d2) << 32) | (unsigned)i;
      }
      cnt += __popcll(mask);
    }
  }
  if (cnt > CAP) cnt = CAP;
  __syncthreads();  // uniform within this path; ensures LDS writes visible
  int out = -1;
  if (cnt <= 64) {
    if (lane < cnt) out = (int)(unsigned)bw[lane];
  } else {
    for (int r = 0; r < 64; ++r) {
      ull mk = ~0ull;
      int mj = -1;
      for (int j = lane; j < cnt; j += 64) {
        ull v = bw[j];
        if (v < mk) { mk = v; mj = j; }
      }
      ull kc = ~mk;
      wave_max_u64(kc);
      ull g = ~__shfl(kc, 63, 64);
      if (mk == g && mj >= 0) bw[mj] = ~0ull;  // unique keys -> exactly one owner
      asm volatile("s_waitcnt lgkmcnt(0)" ::: "memory");
      if (lane == r) out = (int)(unsigned)g;
    }
  }
  nbr[((size_t)b * S + s) * 64 + lane] = (short)out;
}

// ---------------- K_A: fps1 (blocks 0..3) U local MLP (blocks 4..4+BB*MM/8) ----------------
// local branch: pos -> 64 -> 64 -> 128 (tanh each), 8 points per 512-thread block.
__global__ __launch_bounds__(512) void k_fps1_local(
    const float* __restrict__ pos, float* __restrict__ c1,
    const float* __restrict__ w0, const float* __restrict__ b0,
    const float* __restrict__ w1, const float* __restrict__ b1,
    const float* __restrict__ w2, const float* __restrict__ b2,
    float* __restrict__ out) {
  __shared__ __align__(16) char smem[16 * MM + 12 * SS1 + 128];  // 155,776 B
  if (blockIdx.x < BB) {
    int b = blockIdx.x;
    fps_core<MM, SS1, 512>(pos + (size_t)b * MM * 3, c1 + (size_t)b * SS1 * 3, smem);
  } else {
    float* p  = (float*)smem;           // [8][3]
    float* h0 = (float*)smem + 32;      // [8][64]
    float* h1 = (float*)smem + 32 + 512;// [8][64]
    int t = threadIdx.x;
    size_t pid0 = (size_t)(blockIdx.x - BB) * 8;
    if (t < 24) {
      int pp = t / 3, j = t % 3;
      p[pp * 3 + j] = pos[(pid0 + pp) * 3 + j];
    }
    __syncthreads();
    {
      int pp = t >> 6, c = t & 63;
      float acc = b0[c];
      #pragma unroll
      for (int j = 0; j < 3; ++j) acc += p[pp * 3 + j] * w0[j * 64 + c];
      h0[pp * 64 + c] = tanhf(acc);
    }
    __syncthreads();
    {
      int pp = t >> 6, c = t & 63;
      float acc = b1[c];
      #pragma unroll
      for (int j = 0; j < 64; ++j) acc += h0[pp * 64 + j] * w1[j * 64 + c];
      h1[pp * 64 + c] = tanhf(acc);
    }
    __syncthreads();
    #pragma unroll
    for (int r = 0; r < 2; ++r) {
      int o = t + 512 * r;
      int pp = o >> 7, c = o & 127;
      float acc = b2[c];
      #pragma unroll
      for (int j = 0; j < 64; ++j) acc += h1[pp * 64 + j] * w2[j * 128 + c];
      out[(pid0 + pp) * 128 + c] = tanhf(acc);
    }
  }
}

// standalone fps1 (fallback path when scratch aliases d_out: local must run LAST)
__global__ __launch_bounds__(512, 1) void fps1_kernel(const float* __restrict__ pts,
                                                      float* __restrict__ cen) {
  __shared__ __align__(16) char smem[16 * MM + 12 * SS1 + 128];
  fps_core<MM, SS1, 512>(pts + (size_t)blockIdx.x * MM * 3,
                         cen + (size_t)blockIdx.x * SS1 * 3, smem);
}

// standalone local MLP (fallback path), 8 pts per 512-thread block
__global__ __launch_bounds__(512) void local_mlp_kernel(
    const float* __restrict__ pos,
    const float* __restrict__ w0, const float* __restrict__ b0,
    const float* __restrict__ w1, const float* __restrict__ b1,
    const float* __restrict__ w2, const float* __restrict__ b2,
    float* __restrict__ out) {
  __shared__ float p[8][3];
  __shared__ float h0[8][64];
  __shared__ float h1[8][64];
  int t = threadIdx.x;
  size_t pid0 = (size_t)blockIdx.x * 8;
  if (t < 24) {
    int pp = t / 3, j = t % 3;
    p[pp][j] = pos[(pid0 + pp) * 3 + j];
  }
  __syncthreads();
  {
    int pp = t >> 6, c = t & 63;
    float acc = b0[c];
    #pragma unroll
    for (int j = 0; j < 3; ++j) acc += p[pp][j] * w0[j * 64 + c];
    h0[pp][c] = tanhf(acc);
  }
  __syncthreads();
  {
    int pp = t >> 6, c = t & 63;
    float acc = b1[c];
    #pragma unroll
    for (int j = 0; j < 64; ++j) acc += h0[pp][j] * w1[j * 64 + c];
    h1[pp][c] = tanhf(acc);
  }
  __syncthreads();
  #pragma unroll
  for (int r = 0; r < 2; ++r) {
    int o = t + 512 * r;
    int pp = o >> 7, c = o & 127;
    float acc = b2[c];
    #pragma unroll
    for (int j = 0; j < 64; ++j) acc += h1[pp][j] * w2[j * 128 + c];
    out[(pid0 + pp) * 128 + c] = tanhf(acc);
  }
}

// ---------------- K_B: fps2 8-wave (blocks 0..3) U nbr1 (blocks 4..) ----------------
// smem bumped to 96KB -> 1 block/CU: fps2 blocks get EXCLUSIVE CUs (R7's
// single-wave fps2 shared a CU with an 8-wave nbr block and starved at ~1/9
// issue share). nbr at 8 waves/CU is latency-tolerant; fps2 is not.
__global__ __launch_bounds__(512) void k_fps2_nbr1(
    const float* __restrict__ pos, const float* __restrict__ c1,
    float* __restrict__ c2, short* __restrict__ nbr1) {
  __shared__ __align__(16) char smem[98304];  // 96KB: forces 1 block/CU
  if (blockIdx.x < BB) {
    int b = blockIdx.x;
    fps_core<SS1, SS2, 512>(c1 + (size_t)b * SS1 * 3, c2 + (size_t)b * SS2 * 3, smem);
  } else {
    nbr_core<MM, 8>(pos, c1, SS1, 0.04f, nbr1, (ull*)smem, blockIdx.x - BB);
  }
}

// ---------------- K_C: group1 (blocks 0..BB*SS1) U nbr2 (tail blocks) ----------------
// SA1 grouped MLP: feats[64][9] -> 64 -> 128, masked PRE-ACT max over K;
// layer2 register-tiled 8k x 4ch; tanh/bias deferred past the masked max (exact).
__global__ __launch_bounds__(256, 4) void k_group1_nbr2(
    const float* __restrict__ pos, const float* __restrict__ x,
    const float* __restrict__ c1, const short* __restrict__ nbr,
    const float* __restrict__ w0, const float* __restrict__ b0,
    const float* __restrict__ w1, const float* __restrict__ b1,
    float* __restrict__ h1out,
    const float* __restrict__ c2, short* __restrict__ nbr2out) {
  __shared__ __align__(16) char smem[32768];  // nbr2 32KB >= group1 ~24.9KB
  if (blockIdx.x >= BB * SS1) {
    nbr_core<SS1, 4>(c1, c2, SS2, 0.16f, nbr2out, (ull*)smem, blockIdx.x - BB * SS1);
    return;
  }
  float (*feats)[12] = (float(*)[12])smem;                    // 3072 B
  float (*hbuf)[68]  = (float(*)[68])(smem + 3072);           // 17408 B
  float (*Mred)[128] = (float(*)[128])(smem + 3072 + 17408);  // 4096 B
  int* nb            = (int*)(smem + 3072 + 17408 + 4096);    // 256 B
  float* cc          = (float*)(smem + 3072 + 17408 + 4096 + 256);  // 12 B
  int t = threadIdx.x;
  int bs = blockIdx.x;  // b*S1 + s
  int b = bs >> 11;
  if (t < 64) nb[t] = (int)nbr[(size_t)bs * 64 + t];
  if (t < 3) cc[t] = c1[(size_t)bs * 3 + t];
  __syncthreads();
  if (t < 64) {
    int n = nb[t];
    int ni = ((unsigned)n < (unsigned)MM) ? n : 0;  // clamp: replay-safe
    const float* pp = pos + ((size_t)b * MM + ni) * 3;
    const float* xx = x + ((size_t)b * MM + ni) * 3;
    float p0 = pp[0], p1 = pp[1], p2 = pp[2];
    feats[t][0] = p0; feats[t][1] = p1; feats[t][2] = p2;
    feats[t][3] = xx[0]; feats[t][4] = xx[1]; feats[t][5] = xx[2];
    feats[t][6] = p0 - cc[0]; feats[t][7] = p1 - cc[1]; feats[t][8] = p2 - cc[2];
  }
  __syncthreads();
  // layer1: 9 -> 64; thread (k = t>>2, q = t&3) computes 16 channels
  {
    int k = t >> 2, q = t & 3;
    float acc[16];
    #pragma unroll
    for (int i = 0; i < 16; ++i) acc[i] = b0[q * 16 + i];
    #pragma unroll
    for (int j = 0; j < 9; ++j) {
      float f = feats[k][j];
      const float4* wr = (const float4*)(w0 + j * 64 + q * 16);
      #pragma unroll
      for (int i = 0; i < 4; ++i) {
        float4 wvv = wr[i];
        acc[4 * i + 0] += f * wvv.x;
        acc[4 * i + 1] += f * wvv.y;
        acc[4 * i + 2] += f * wvv.z;
        acc[4 * i + 3] += f * wvv.w;
      }
    }
    #pragma unroll
    for (int i = 0; i < 16; ++i) hbuf[k][q * 16 + i] = tanhf(acc[i]);
  }
  __syncthreads();
  // layer2: hidden[64][64] x W1[64][128], masked PRE-ACT max over k
  {
    int kt = t >> 5;  // 0..7
    int ct = t & 31;  // 0..31
    float acc[8][4];
    #pragma unroll
    for (int a = 0; a < 8; ++a)
      #pragma unroll
      for (int ci = 0; ci < 4; ++ci) acc[a][ci] = 0.f;
    const float* wbase = w1 + ct * 4;
    for (int j = 0; j < 64; j += 2) {
      float2 fv[8];
      #pragma unroll
      for (int kk = 0; kk < 8; ++kk)
        fv[kk] = *(const float2*)&hbuf[kt * 8 + kk][j];
      float wja[4], wjb[4];
      *(float4*)&wja[0] = *(const float4*)(wbase + (size_t)j * 128);
      *(float4*)&wjb[0] = *(const float4*)(wbase + (size_t)(j + 1) * 128);
      #pragma unroll
      for (int kk = 0; kk < 8; ++kk)
        #pragma unroll
        for (int ci = 0; ci < 4; ++ci) {
          acc[kk][ci] += fv[kk].x * wja[ci];
          acc[kk][ci] += fv[kk].y * wjb[ci];
        }
    }
    float m[4];
    #pragma unroll
    for (int ci = 0; ci < 4; ++ci) m[ci] = -INFINITY;
    #pragma unroll
    for (int kk = 0; kk < 8; ++kk) {
      if (nb[kt * 8 + kk] >= 0) {
        #pragma unroll
        for (int ci = 0; ci < 4; ++ci) m[ci] = fmaxf(m[ci], acc[kk][ci]);
      }
    }
    #pragma unroll
    for (int ci = 0; ci < 4; ++ci) Mred[kt][ct * 4 + ci] = m[ci];
  }
  __syncthreads();
  if (t < 128) {
    float mxv = Mred[0][t];
    #pragma unroll
    for (int r = 1; r < 8; ++r) mxv = fmaxf(mxv, Mred[r][t]);
    h1out[(size_t)bs * 128 + t] = tanhf(mxv + b1[t]);  // bias+tanh after max: exact
  }
}

// ---------------- SA2 grouped MLP: feats[64][131] -> 128 -> 256, masked max over K ----------------
__global__ __launch_bounds__(256, 4) void group2_kernel(
    const float* __restrict__ h1, const float* __restrict__ c1,
    const float* __restrict__ c2, const short* __restrict__ nbr,
    const float* __restrict__ w0, const float* __restrict__ b0,
    const float* __restrict__ w1, const float* __restrict__ b1,
    float* __restrict__ h2out) {
  __shared__ float fb[64][132];  // feats (131) then reused as hidden (128)
  __shared__ float Mred[8][256];
  __shared__ int nb[64];
  __shared__ float cc[3];
  int t = threadIdx.x;
  int bs = blockIdx.x;  // b*S2 + s
  int b = bs >> 9;
  if (t < 64) nb[t] = (int)nbr[(size_t)bs * 64 + t];
  if (t < 3) cc[t] = c2[(size_t)bs * 3 + t];
  __syncthreads();
  {
    int k = t >> 2, q = t & 3;
    int n = nb[k];
    int ni = ((unsigned)n < (unsigned)SS1) ? n : 0;  // clamp: replay-safe
    const float* hrow = h1 + ((size_t)b * SS1 + ni) * 128;
    #pragma unroll
    for (int i = 0; i < 32; ++i) fb[k][q * 32 + i] = hrow[q * 32 + i];
    if (q == 0) {
      const float* pr = c1 + ((size_t)b * SS1 + ni) * 3;
      fb[k][128] = pr[0] - cc[0];
      fb[k][129] = pr[1] - cc[1];
      fb[k][130] = pr[2] - cc[2];
    }
  }
  __syncthreads();
  float acc1[32];
  {
    int k = t >> 2, q = t & 3;
    #pragma unroll
    for (int i = 0; i < 32; ++i) acc1[i] = b0[q * 32 + i];
    for (int j = 0; j < 131; ++j) {
      float f = fb[k][j];
      const float4* wr = (const float4*)(w0 + (size_t)j * 128 + q * 32);
      #pragma unroll
      for (int i = 0; i < 8; ++i) {
        float4 wvv = wr[i];
        acc1[4 * i + 0] += f * wvv.x;
        acc1[4 * i + 1] += f * wvv.y;
        acc1[4 * i + 2] += f * wvv.z;
        acc1[4 * i + 3] += f * wvv.w;
      }
    }
  }
  __syncthreads();
  {
    int k = t >> 2, q = t & 3;
    #pragma unroll
    for (int i = 0; i < 32; ++i) fb[k][q * 32 + i] = tanhf(acc1[i]);
  }
  __syncthreads();
  {
    int kt = t >> 5;  // 0..7
    int ct = t & 31;  // 0..31
    float acc[8][8];
    #pragma unroll
    for (int a = 0; a < 8; ++a)
      #pragma unroll
      for (int c2i = 0; c2i < 8; ++c2i) acc[a][c2i] = 0.f;
    const float* wbase = w1 + ct * 8;
    for (int j = 0; j < 128; j += 2) {
      float2 fv[8];
      #pragma unroll
      for (int kk = 0; kk < 8; ++kk)
        fv[kk] = *(const float2*)&fb[kt * 8 + kk][j];
      float wja[8], wjb[8];
      const float4* wp0 = (const float4*)(wbase + (size_t)j * 256);
      const float4* wp1 = (const float4*)(wbase + (size_t)(j + 1) * 256);
      *(float4*)&wja[0] = wp0[0];
      *(float4*)&wja[4] = wp0[1];
      *(float4*)&wjb[0] = wp1[0];
      *(float4*)&wjb[4] = wp1[1];
      #pragma unroll
      for (int kk = 0; kk < 8; ++kk)
        #pragma unroll
        for (int ci = 0; ci < 8; ++ci) {
          acc[kk][ci] += fv[kk].x * wja[ci];
          acc[kk][ci] += fv[kk].y * wjb[ci];
        }
    }
    float m[8];
    #pragma unroll
    for (int ci = 0; ci < 8; ++ci) m[ci] = -INFINITY;
    #pragma unroll
    for (int kk = 0; kk < 8; ++kk) {
      if (nb[kt * 8 + kk] >= 0) {
        #pragma unroll
        for (int ci = 0; ci < 8; ++ci) m[ci] = fmaxf(m[ci], acc[kk][ci]);
      }
    }
    #pragma unroll
    for (int ci = 0; ci < 8; ++ci) Mred[kt][ct * 8 + ci] = m[ci];
  }
  __syncthreads();
  if (t < 256) {
    float mxv = Mred[0][t];
    #pragma unroll
    for (int r = 1; r < 8; ++r) mxv = fmaxf(mxv, Mred[r][t]);
    h2out[(size_t)bs * 256 + t] = tanhf(mxv + b1[t]);  // bias+tanh after max: exact
  }
}

// ---------------- global max over centers ----------------
__global__ __launch_bounds__(256) void gmax_kernel(const float* __restrict__ h2,
                                                   float* __restrict__ out) {
  int b = blockIdx.x, c = threadIdx.x;
  float mx = -INFINITY;
  for (int s = 0; s < SS2; ++s)
    mx = fmaxf(mx, h2[((size_t)b * SS2 + s) * 256 + c]);
  out[(size_t)BB * MM * 128 + b * 256 + c] = mx;
}

extern "C" void kernel_launch(void* const* d_in, const int* in_sizes, int n_in,
                              void* d_out, int out_size, void* d_ws, size_t ws_size,
                              hipStream_t stream) {
  // Reference is pure float32: all inputs AND the output buffer are f32.
  const float* x    = (const float*)d_in[0];
  const float* pos  = (const float*)d_in[1];
  const float* lw0  = (const float*)d_in[2];
  const float* lb0  = (const float*)d_in[3];
  const float* lw1  = (const float*)d_in[4];
  const float* lb1  = (const float*)d_in[5];
  const float* lw2  = (const float*)d_in[6];
  const float* lb2  = (const float*)d_in[7];
  const float* g1w0 = (const float*)d_in[8];
  const float* g1b0 = (const float*)d_in[9];
  const float* g1w1 = (const float*)d_in[10];
  const float* g1b1 = (const float*)d_in[11];
  const float* g2w0 = (const float*)d_in[12];
  const float* g2b0 = (const float*)d_in[13];
  const float* g2w1 = (const float*)d_in[14];
  const float* g2b1 = (const float*)d_in[15];
  float* out = (float*)d_out;

  // Scratch (7.73 MB with i16 neighbor indices): prefer d_ws; fall back to
  // the local-output region of d_out (16.8 MB). With d_ws, local MLP can be
  // fused into the fps1 launch (it writes d_out directly); without, local
  // must run LAST since scratch aliases its output region.
  const size_t NEED = 7725056;
  bool has_ws = (ws_size >= NEED);
  char* sc = has_ws ? (char*)d_ws : (char*)d_out;
  float* h1   = (float*)(sc + 0);        // 4*2048*128 f32 = 4,194,304 B
  float* h2   = (float*)(sc + 4194304);  // 4*512*256 f32  = 2,097,152 B
  float* c1   = (float*)(sc + 6291456);  // 4*2048*3 f32   =    98,304 B
  float* c2   = (float*)(sc + 6389760);  // 4*512*3 f32    =    24,576 B
  short* nbr1 = (short*)(sc + 6414336);  // 4*2048*64 i16  = 1,048,576 B
  short* nbr2 = (short*)(sc + 7462912);  // 4*512*64 i16   =   262,144 B (end 7,725,056)

  if (has_ws) {
    // fused schedule: fps1 hides local_mlp; fps2 hides nbr1; group1 hides nbr2
    k_fps1_local<<<BB + BB * MM / 8, 512, 0, stream>>>(
        pos, c1, lw0, lb0, lw1, lb1, lw2, lb2, out);
  } else {
    fps1_kernel<<<BB, 512, 0, stream>>>(pos, c1);
  }
  k_fps2_nbr1<<<BB + BB * SS1 / 8, 512, 0, stream>>>(pos, c1, c2, nbr1);
  k_group1_nbr2<<<BB * SS1 + BB * SS2 / 4, 256, 0, stream>>>(
      pos, x, c1, nbr1, g1w0, g1b0, g1w1, g1b1, h1, c2, nbr2);
  group2_kernel<<<BB * SS2, 256, 0, stream>>>(h1, c1, c2, nbr2, g2w0, g2b0, g2w1, g2b1, h2);
  gmax_kernel<<<BB, 256, 0, stream>>>(h2, out);
  if (!has_ws) {
    local_mlp_kernel<<<BB * MM / 8, 512, 0, stream>>>(pos, lw0, lb0, lw1, lb1, lw2, lb2, out);
  }
}

// Round 9
// 3877.802 us; speedup vs baseline: 1.0162x; 1.0035x over previous
//
#include <hip/hip_runtime.h>
#include <hip/hip_bf16.h>

#define BB 4
#define MM 8192
#define SS1 2048
#define SS2 512

using ull = unsigned long long;
typedef float f32x2 __attribute__((ext_vector_type(2)));

// ---------------- packed f32 helpers (VOP3P, per-element IEEE-identical) ----------------
__device__ __forceinline__ f32x2 pk_add(f32x2 a, f32x2 b) {
  f32x2 r; asm("v_pk_add_f32 %0, %1, %2" : "=v"(r) : "v"(a), "v"(b)); return r;
}
__device__ __forceinline__ f32x2 pk_mul(f32x2 a, f32x2 b) {
  f32x2 r; asm("v_pk_mul_f32 %0, %1, %2" : "=v"(r) : "v"(a), "v"(b)); return r;
}

// ---------------- DPP helpers ----------
template <int CTRL>
__device__ __forceinline__ void dpp_max_step(ull& k) {
  unsigned lo = (unsigned)k, hi = (unsigned)(k >> 32);
  unsigned plo = (unsigned)__builtin_amdgcn_update_dpp(0, (int)lo, CTRL, 0xF, 0xF, true);
  unsigned phi = (unsigned)__builtin_amdgcn_update_dpp(0, (int)hi, CTRL, 0xF, 0xF, true);
  ull pk = ((ull)phi << 32) | plo;
  if (pk > k) k = pk;
}

// full-wave max, result in lane 63
__device__ __forceinline__ void wave_max_u64(ull& k) {
  dpp_max_step<0x111>(k);  // row_shr:1
  dpp_max_step<0x112>(k);  // row_shr:2
  dpp_max_step<0x114>(k);  // row_shr:4
  dpp_max_step<0x118>(k);  // row_shr:8
  dpp_max_step<0x142>(k);  // row_bcast:15
  dpp_max_step<0x143>(k);  // row_bcast:31 -> lane63 = wave max
}

// 8-lane max (entries in lanes 0..7), result in lane 7: 3 dependent steps
__device__ __forceinline__ void row8_max_u64(ull& k) {
  dpp_max_step<0x111>(k);
  dpp_max_step<0x112>(k);
  dpp_max_step<0x114>(k);
}

// ---------------- farthest point sampling core (8 waves) ----------------
// Exact f32 numpy semantics: contract-off rounding order preserved exactly
// (dx*dx rounded; dy*dy rounded; sum rounded; dz*dz rounded; sum rounded) --
// pk ops are per-element IEEE-identical to the scalar forms, and a+(-c) is
// bit-identical to a-c. argmax ties -> lowest index via key (d2<<32)|~idx.
// R20: body uses v_pk_mul/add_f32 (2 f32/lane/instr): 8 scalar ops/elem -> 8
// pk ops/PAIR, cutting total VALU issue ~35%. Tail reverted to R7's proven
// kb+row8+readlane (R8's ds_max_u64 atomic was +74us worse, measured).
template <int MP, int NSEL, int THREADS>
__device__ __forceinline__ void fps_core(const float* __restrict__ p,
                                         float* __restrict__ c_out,
                                         char* smem) {
  constexpr int E = MP / THREADS;
  constexpr int P = E / 2;
  constexpr int W = THREADS / 64;
  static_assert(W == 8, "row8 tail assumes exactly 8 waves");
  static_assert(MP % THREADS == 0 && (E % 2) == 0, "geometry");
  float4* sp = (float4*)smem;                                    // 16*MP
  float* cbuf = (float*)(smem + sizeof(float4) * MP);            // 12*NSEL
  ull* kb = (ull*)(smem + sizeof(float4) * MP + sizeof(float) * NSEL * 3);  // 2*W*8
  int t = threadIdx.x;
  int lane = t & 63, wv = t >> 6;
  for (int i = t; i < MP; i += THREADS)
    sp[i] = make_float4(p[i * 3 + 0], p[i * 3 + 1], p[i * 3 + 2], 0.f);
  __syncthreads();
  // register-resident points as packed pairs (elems 2p and 2p+1) + running dd
  f32x2 X[P], Y[P], Z[P], D[P];
  #pragma unroll
  for (int pp = 0; pp < P; ++pp) {
    float4 qa = sp[t + (2 * pp + 0) * THREADS];  // conflict-free ds_read_b128
    float4 qb = sp[t + (2 * pp + 1) * THREADS];
    X[pp] = (f32x2){qa.x, qb.x};
    Y[pp] = (f32x2){qa.y, qb.y};
    Z[pp] = (f32x2){qa.z, qb.z};
    D[pp] = (f32x2){INFINITY, INFINITY};
  }
  float4 c0 = sp[0];
  float cx = c0.x, cy = c0.y, cz = c0.z;
  if (t == 0) { cbuf[0] = cx; cbuf[1] = cy; cbuf[2] = cz; }
  int par = 0;
  for (int it = 1; it < NSEL; ++it) {
    float bd = -1.0f;
    int be = 0;
    float ncx = -cx, ncy = -cy, ncz = -cz;  // a+(-c) == a-c bit-exactly
    f32x2 NX = (f32x2){ncx, ncx}, NY = (f32x2){ncy, ncy}, NZ = (f32x2){ncz, ncz};
    #pragma unroll
    for (int pp = 0; pp < P; ++pp) {
      f32x2 dx = pk_add(X[pp], NX);
      f32x2 dy = pk_add(Y[pp], NY);
      f32x2 dz = pk_add(Z[pp], NZ);
      f32x2 sx = pk_mul(dx, dx);
      f32x2 sy = pk_mul(dy, dy);
      f32x2 s1 = pk_add(sx, sy);
      f32x2 sz = pk_mul(dz, dz);
      f32x2 nd = pk_add(s1, sz);
      float d0 = fminf(D[pp].x, nd.x);
      float d1 = fminf(D[pp].y, nd.y);
      D[pp].x = d0;
      D[pp].y = d1;
      if (d0 > bd) { bd = d0; be = 2 * pp; }      // ascending e, strict >:
      if (d1 > bd) { bd = d1; be = 2 * pp + 1; }  // lowest e kept (lowest idx)
    }
    int bidx = t + be * THREADS;  // idx monotone in e -> in-thread ties exact
    ull k = ((ull)__float_as_uint(bd) << 32) | (unsigned)(~bidx);
    wave_max_u64(k);
    if (lane == 63) kb[par * W + wv] = k;
    __syncthreads();
    ull v = 0;
    if (lane < W) v = kb[par * W + lane];  // one predicated ds_read_b64 per wave
    row8_max_u64(v);                       // lane7 = block max (W==8)
    unsigned glo = __builtin_amdgcn_readlane((unsigned)v, 7);  // low word: ~bidx
    int widx = (int)(~glo) & (MP - 1);  // mask: replay-safe no-op
    float4 cw = sp[widx];  // uniform address -> LDS broadcast
    cx = cw.x; cy = cw.y; cz = cw.z;
    if (t == 0) {
      cbuf[it * 3 + 0] = cx;
      cbuf[it * 3 + 1] = cy;
      cbuf[it * 3 + 2] = cz;
    }
    par ^= 1;
  }
  __syncthreads();
  for (int i = t; i < NSEL * 3; i += THREADS) c_out[i] = cbuf[i];
}

// ---------------- ball query core: 64 nearest with d2 <= R2, ties by lower index ----------------
// One wave per center, NW waves per block. Output indices i16 (-1..8191 lossless).
template <int MP, int NW>
__device__ __forceinline__ void nbr_core(const float* __restrict__ pts,
                                         const float* __restrict__ cen, int S,
                                         float R2, short* __restrict__ nbr,
                                         ull* buf, int blk) {
  constexpr int CAP = 1024;
  int t = threadIdx.x;
  int wv = t >> 6, lane = t & 63;
  int gw = blk * NW + wv;
  int b = gw / S, s = gw % S;
  const float* p = pts + (size_t)b * MP * 3;
  const float* c = cen + ((size_t)b * S + s) * 3;
  float cx = c[0], cy = c[1], cz = c[2];
  ull* bw = buf + (size_t)wv * CAP;
  int cnt = 0;
  {
    #pragma clang fp contract(off)
    for (int i0 = 0; i0 < MP; i0 += 64) {
      int i = i0 + lane;
      float dx = p[i * 3 + 0] - cx;
      float dy = p[i * 3 + 1] - cy;
      float dz = p[i * 3 + 2] - cz;
      float d2 = dx * dx;
      d2 += dy * dy;
      d2 += dz * dz;
      bool in = (d2 <= R2);
      ull mask = __ballot(in);
      if (in) {
        int off = __popcll(mask & ((1ull << lane) - 1ull));
        int pos = cnt + off;
        if (pos < CAP)
          bw[pos] = ((ull)__float_as_uint(d2) << 32) | (unsigned)i;
      }
      cnt += __popcll(mask);
    }
  }
  if (cnt > CAP) cnt = CAP;
  __syncthreads();  // uniform within this path; ensures LDS writes visible
  int out = -1;
  if (cnt <= 64) {
    if (lane < cnt) out = (int)(unsigned)bw[lane];
  } else {
    for (int r = 0; r < 64; ++r) {
      ull mk = ~0ull;
      int mj = -1;
      for (int j = lane; j < cnt; j += 64) {
        ull v = bw[j];
        if (v < mk) { mk = v; mj = j; }
      }
      ull kc = ~mk;
      wave_max_u64(kc);
      ull g = ~__shfl(kc, 63, 64);
      if (mk == g && mj >= 0) bw[mj] = ~0ull;  // unique keys -> exactly one owner
      asm volatile("s_waitcnt lgkmcnt(0)" ::: "memory");
      if (lane == r) out = (int)(unsigned)g;
    }
  }
  nbr[((size_t)b * S + s) * 64 + lane] = (short)out;
}

// ---------------- K_A: fps1 (blocks 0..3) U local MLP (blocks 4..4+BB*MM/8) ----------------
// local branch: pos -> 64 -> 64 -> 128 (tanh each), 8 points per 512-thread block.
__global__ __launch_bounds__(512) void k_fps1_local(
    const float* __restrict__ pos, float* __restrict__ c1,
    const float* __restrict__ w0, const float* __restrict__ b0,
    const float* __restrict__ w1, const float* __restrict__ b1,
    const float* __restrict__ w2, const float* __restrict__ b2,
    float* __restrict__ out) {
  __shared__ __align__(16) char smem[16 * MM + 12 * SS1 + 128];  // 155,776 B
  if (blockIdx.x < BB) {
    int b = blockIdx.x;
    fps_core<MM, SS1, 512>(pos + (size_t)b * MM * 3, c1 + (size_t)b * SS1 * 3, smem);
  } else {
    float* p  = (float*)smem;           // [8][3]
    float* h0 = (float*)smem + 32;      // [8][64]
    float* h1 = (float*)smem + 32 + 512;// [8][64]
    int t = threadIdx.x;
    size_t pid0 = (size_t)(blockIdx.x - BB) * 8;
    if (t < 24) {
      int pp = t / 3, j = t % 3;
      p[pp * 3 + j] = pos[(pid0 + pp) * 3 + j];
    }
    __syncthreads();
    {
      int pp = t >> 6, c = t & 63;
      float acc = b0[c];
      #pragma unroll
      for (int j = 0; j < 3; ++j) acc += p[pp * 3 + j] * w0[j * 64 + c];
      h0[pp * 64 + c] = tanhf(acc);
    }
    __syncthreads();
    {
      int pp = t >> 6, c = t & 63;
      float acc = b1[c];
      #pragma unroll
      for (int j = 0; j < 64; ++j) acc += h0[pp * 64 + j] * w1[j * 64 + c];
      h1[pp * 64 + c] = tanhf(acc);
    }
    __syncthreads();
    #pragma unroll
    for (int r = 0; r < 2; ++r) {
      int o = t + 512 * r;
      int pp = o >> 7, c = o & 127;
      float acc = b2[c];
      #pragma unroll
      for (int j = 0; j < 64; ++j) acc += h1[pp * 64 + j] * w2[j * 128 + c];
      out[(pid0 + pp) * 128 + c] = tanhf(acc);
    }
  }
}

// standalone fps1 (fallback path when scratch aliases d_out: local must run LAST)
__global__ __launch_bounds__(512, 1) void fps1_kernel(const float* __restrict__ pts,
                                                      float* __restrict__ cen) {
  __shared__ __align__(16) char smem[16 * MM + 12 * SS1 + 128];
  fps_core<MM, SS1, 512>(pts + (size_t)blockIdx.x * MM * 3,
                         cen + (size_t)blockIdx.x * SS1 * 3, smem);
}

// standalone local MLP (fallback path), 8 pts per 512-thread block
__global__ __launch_bounds__(512) void local_mlp_kernel(
    const float* __restrict__ pos,
    const float* __restrict__ w0, const float* __restrict__ b0,
    const float* __restrict__ w1, const float* __restrict__ b1,
    const float* __restrict__ w2, const float* __restrict__ b2,
    float* __restrict__ out) {
  __shared__ float p[8][3];
  __shared__ float h0[8][64];
  __shared__ float h1[8][64];
  int t = threadIdx.x;
  size_t pid0 = (size_t)blockIdx.x * 8;
  if (t < 24) {
    int pp = t / 3, j = t % 3;
    p[pp][j] = pos[(pid0 + pp) * 3 + j];
  }
  __syncthreads();
  {
    int pp = t >> 6, c = t & 63;
    float acc = b0[c];
    #pragma unroll
    for (int j = 0; j < 3; ++j) acc += p[pp][j] * w0[j * 64 + c];
    h0[pp][c] = tanhf(acc);
  }
  __syncthreads();
  {
    int pp = t >> 6, c = t & 63;
    float acc = b1[c];
    #pragma unroll
    for (int j = 0; j < 64; ++j) acc += h0[pp][j] * w1[j * 64 + c];
    h1[pp][c] = tanhf(acc);
  }
  __syncthreads();
  #pragma unroll
  for (int r = 0; r < 2; ++r) {
    int o = t + 512 * r;
    int pp = o >> 7, c = o & 127;
    float acc = b2[c];
    #pragma unroll
    for (int j = 0; j < 64; ++j) acc += h1[pp][j] * w2[j * 128 + c];
    out[(pid0 + pp) * 128 + c] = tanhf(acc);
  }
}

// ---------------- K_B: fps2 8-wave (blocks 0..3) U nbr1 (blocks 4..) ----------------
// smem 96KB -> 1 block/CU: fps2 blocks get EXCLUSIVE CUs (proven +120us in R8
// vs R7's shared-CU single-wave). nbr at 8 waves/CU is latency-tolerant.
__global__ __launch_bounds__(512) void k_fps2_nbr1(
    const float* __restrict__ pos, const float* __restrict__ c1,
    float* __restrict__ c2, short* __restrict__ nbr1) {
  __shared__ __align__(16) char smem[98304];  // 96KB: forces 1 block/CU
  if (blockIdx.x < BB) {
    int b = blockIdx.x;
    fps_core<SS1, SS2, 512>(c1 + (size_t)b * SS1 * 3, c2 + (size_t)b * SS2 * 3, smem);
  } else {
    nbr_core<MM, 8>(pos, c1, SS1, 0.04f, nbr1, (ull*)smem, blockIdx.x - BB);
  }
}

// ---------------- K_C: group1 (blocks 0..BB*SS1) U nbr2 (tail blocks) ----------------
// SA1 grouped MLP: feats[64][9] -> 64 -> 128, masked PRE-ACT max over K;
// layer2 register-tiled 8k x 4ch; tanh/bias deferred past the masked max (exact).
__global__ __launch_bounds__(256, 4) void k_group1_nbr2(
    const float* __restrict__ pos, const float* __restrict__ x,
    const float* __restrict__ c1, const short* __restrict__ nbr,
    const float* __restrict__ w0, const float* __restrict__ b0,
    const float* __restrict__ w1, const float* __restrict__ b1,
    float* __restrict__ h1out,
    const float* __restrict__ c2, short* __restrict__ nbr2out) {
  __shared__ __align__(16) char smem[32768];  // nbr2 32KB >= group1 ~24.9KB
  if (blockIdx.x >= BB * SS1) {
    nbr_core<SS1, 4>(c1, c2, SS2, 0.16f, nbr2out, (ull*)smem, blockIdx.x - BB * SS1);
    return;
  }
  float (*feats)[12] = (float(*)[12])smem;                    // 3072 B
  float (*hbuf)[68]  = (float(*)[68])(smem + 3072);           // 17408 B
  float (*Mred)[128] = (float(*)[128])(smem + 3072 + 17408);  // 4096 B
  int* nb            = (int*)(smem + 3072 + 17408 + 4096);    // 256 B
  float* cc          = (float*)(smem + 3072 + 17408 + 4096 + 256);  // 12 B
  int t = threadIdx.x;
  int bs = blockIdx.x;  // b*S1 + s
  int b = bs >> 11;
  if (t < 64) nb[t] = (int)nbr[(size_t)bs * 64 + t];
  if (t < 3) cc[t] = c1[(size_t)bs * 3 + t];
  __syncthreads();
  if (t < 64) {
    int n = nb[t];
    int ni = ((unsigned)n < (unsigned)MM) ? n : 0;  // clamp: replay-safe
    const float* pp = pos + ((size_t)b * MM + ni) * 3;
    const float* xx = x + ((size_t)b * MM + ni) * 3;
    float p0 = pp[0], p1 = pp[1], p2 = pp[2];
    feats[t][0] = p0; feats[t][1] = p1; feats[t][2] = p2;
    feats[t][3] = xx[0]; feats[t][4] = xx[1]; feats[t][5] = xx[2];
    feats[t][6] = p0 - cc[0]; feats[t][7] = p1 - cc[1]; feats[t][8] = p2 - cc[2];
  }
  __syncthreads();
  // layer1: 9 -> 64; thread (k = t>>2, q = t&3) computes 16 channels
  {
    int k = t >> 2, q = t & 3;
    float acc[16];
    #pragma unroll
    for (int i = 0; i < 16; ++i) acc[i] = b0[q * 16 + i];
    #pragma unroll
    for (int j = 0; j < 9; ++j) {
      float f = feats[k][j];
      const float4* wr = (const float4*)(w0 + j * 64 + q * 16);
      #pragma unroll
      for (int i = 0; i < 4; ++i) {
        float4 wvv = wr[i];
        acc[4 * i + 0] += f * wvv.x;
        acc[4 * i + 1] += f * wvv.y;
        acc[4 * i + 2] += f * wvv.z;
        acc[4 * i + 3] += f * wvv.w;
      }
    }
    #pragma unroll
    for (int i = 0; i < 16; ++i) hbuf[k][q * 16 + i] = tanhf(acc[i]);
  }
  __syncthreads();
  // layer2: hidden[64][64] x W1[64][128], masked PRE-ACT max over k
  {
    int kt = t >> 5;  // 0..7
    int ct = t & 31;  // 0..31
    float acc[8][4];
    #pragma unroll
    for (int a = 0; a < 8; ++a)
      #pragma unroll
      for (int ci = 0; ci < 4; ++ci) acc[a][ci] = 0.f;
    const float* wbase = w1 + ct * 4;
    for (int j = 0; j < 64; j += 2) {
      float2 fv[8];
      #pragma unroll
      for (int kk = 0; kk < 8; ++kk)
        fv[kk] = *(const float2*)&hbuf[kt * 8 + kk][j];
      float wja[4], wjb[4];
      *(float4*)&wja[0] = *(const float4*)(wbase + (size_t)j * 128);
      *(float4*)&wjb[0] = *(const float4*)(wbase + (size_t)(j + 1) * 128);
      #pragma unroll
      for (int kk = 0; kk < 8; ++kk)
        #pragma unroll
        for (int ci = 0; ci < 4; ++ci) {
          acc[kk][ci] += fv[kk].x * wja[ci];
          acc[kk][ci] += fv[kk].y * wjb[ci];
        }
    }
    float m[4];
    #pragma unroll
    for (int ci = 0; ci < 4; ++ci) m[ci] = -INFINITY;
    #pragma unroll
    for (int kk = 0; kk < 8; ++kk) {
      if (nb[kt * 8 + kk] >= 0) {
        #pragma unroll
        for (int ci = 0; ci < 4; ++ci) m[ci] = fmaxf(m[ci], acc[kk][ci]);
      }
    }
    #pragma unroll
    for (int ci = 0; ci < 4; ++ci) Mred[kt][ct * 4 + ci] = m[ci];
  }
  __syncthreads();
  if (t < 128) {
    float mxv = Mred[0][t];
    #pragma unroll
    for (int r = 1; r < 8; ++r) mxv = fmaxf(mxv, Mred[r][t]);
    h1out[(size_t)bs * 128 + t] = tanhf(mxv + b1[t]);  // bias+tanh after max: exact
  }
}

// ---------------- SA2 grouped MLP: feats[64][131] -> 128 -> 256, masked max over K ----------------
__global__ __launch_bounds__(256, 4) void group2_kernel(
    const float* __restrict__ h1, const float* __restrict__ c1,
    const float* __restrict__ c2, const short* __restrict__ nbr,
    const float* __restrict__ w0, const float* __restrict__ b0,
    const float* __restrict__ w1, const float* __restrict__ b1,
    float* __restrict__ h2out) {
  __shared__ float fb[64][132];  // feats (131) then reused as hidden (128)
  __shared__ float Mred[8][256];
  __shared__ int nb[64];
  __shared__ float cc[3];
  int t = threadIdx.x;
  int bs = blockIdx.x;  // b*S2 + s
  int b = bs >> 9;
  if (t < 64) nb[t] = (int)nbr[(size_t)bs * 64 + t];
  if (t < 3) cc[t] = c2[(size_t)bs * 3 + t];
  __syncthreads();
  {
    int k = t >> 2, q = t & 3;
    int n = nb[k];
    int ni = ((unsigned)n < (unsigned)SS1) ? n : 0;  // clamp: replay-safe
    const float* hrow = h1 + ((size_t)b * SS1 + ni) * 128;
    #pragma unroll
    for (int i = 0; i < 32; ++i) fb[k][q * 32 + i] = hrow[q * 32 + i];
    if (q == 0) {
      const float* pr = c1 + ((size_t)b * SS1 + ni) * 3;
      fb[k][128] = pr[0] - cc[0];
      fb[k][129] = pr[1] - cc[1];
      fb[k][130] = pr[2] - cc[2];
    }
  }
  __syncthreads();
  float acc1[32];
  {
    int k = t >> 2, q = t & 3;
    #pragma unroll
    for (int i = 0; i < 32; ++i) acc1[i] = b0[q * 32 + i];
    for (int j = 0; j < 131; ++j) {
      float f = fb[k][j];
      const float4* wr = (const float4*)(w0 + (size_t)j * 128 + q * 32);
      #pragma unroll
      for (int i = 0; i < 8; ++i) {
        float4 wvv = wr[i];
        acc1[4 * i + 0] += f * wvv.x;
        acc1[4 * i + 1] += f * wvv.y;
        acc1[4 * i + 2] += f * wvv.z;
        acc1[4 * i + 3] += f * wvv.w;
      }
    }
  }
  __syncthreads();
  {
    int k = t >> 2, q = t & 3;
    #pragma unroll
    for (int i = 0; i < 32; ++i) fb[k][q * 32 + i] = tanhf(acc1[i]);
  }
  __syncthreads();
  {
    int kt = t >> 5;  // 0..7
    int ct = t & 31;  // 0..31
    float acc[8][8];
    #pragma unroll
    for (int a = 0; a < 8; ++a)
      #pragma unroll
      for (int c2i = 0; c2i < 8; ++c2i) acc[a][c2i] = 0.f;
    const float* wbase = w1 + ct * 8;
    for (int j = 0; j < 128; j += 2) {
      float2 fv[8];
      #pragma unroll
      for (int kk = 0; kk < 8; ++kk)
        fv[kk] = *(const float2*)&fb[kt * 8 + kk][j];
      float wja[8], wjb[8];
      const float4* wp0 = (const float4*)(wbase + (size_t)j * 256);
      const float4* wp1 = (const float4*)(wbase + (size_t)(j + 1) * 256);
      *(float4*)&wja[0] = wp0[0];
      *(float4*)&wja[4] = wp0[1];
      *(float4*)&wjb[0] = wp1[0];
      *(float4*)&wjb[4] = wp1[1];
      #pragma unroll
      for (int kk = 0; kk < 8; ++kk)
        #pragma unroll
        for (int ci = 0; ci < 8; ++ci) {
          acc[kk][ci] += fv[kk].x * wja[ci];
          acc[kk][ci] += fv[kk].y * wjb[ci];
        }
    }
    float m[8];
    #pragma unroll
    for (int ci = 0; ci < 8; ++ci) m[ci] = -INFINITY;
    #pragma unroll
    for (int kk = 0; kk < 8; ++kk) {
      if (nb[kt * 8 + kk] >= 0) {
        #pragma unroll
        for (int ci = 0; ci < 8; ++ci) m[ci] = fmaxf(m[ci], acc[kk][ci]);
      }
    }
    #pragma unroll
    for (int ci = 0; ci < 8; ++ci) Mred[kt][ct * 8 + ci] = m[ci];
  }
  __syncthreads();
  if (t < 256) {
    float mxv = Mred[0][t];
    #pragma unroll
    for (int r = 1; r < 8; ++r) mxv = fmaxf(mxv, Mred[r][t]);
    h2out[(size_t)bs * 256 + t] = tanhf(mxv + b1[t]);  // bias+tanh after max: exact
  }
}

// ---------------- global max over centers ----------------
__global__ __launch_bounds__(256) void gmax_kernel(const float* __restrict__ h2,
                                                   float* __restrict__ out) {
  int b = blockIdx.x, c = threadIdx.x;
  float mx = -INFINITY;
  for (int s = 0; s < SS2; ++s)
    mx = fmaxf(mx, h2[((size_t)b * SS2 + s) * 256 + c]);
  out[(size_t)BB * MM * 128 + b * 256 + c] = mx;
}

extern "C" void kernel_launch(void* const* d_in, const int* in_sizes, int n_in,
                              void* d_out, int out_size, void* d_ws, size_t ws_size,
                              hipStream_t stream) {
  // Reference is pure float32: all inputs AND the output buffer are f32.
  const float* x    = (const float*)d_in[0];
  const float* pos  = (const float*)d_in[1];
  const float* lw0  = (const float*)d_in[2];
  const float* lb0  = (const float*)d_in[3];
  const float* lw1  = (const float*)d_in[4];
  const float* lb1  = (const float*)d_in[5];
  const float* lw2  = (const float*)d_in[6];
  const float* lb2  = (const float*)d_in[7];
  const float* g1w0 = (const float*)d_in[8];
  const float* g1b0 = (const float*)d_in[9];
  const float* g1w1 = (const float*)d_in[10];
  const float* g1b1 = (const float*)d_in[11];
  const float* g2w0 = (const float*)d_in[12];
  const float* g2b0 = (const float*)d_in[13];
  const float* g2w1 = (const float*)d_in[14];
  const float* g2b1 = (const float*)d_in[15];
  float* out = (float*)d_out;

  // Scratch (7.73 MB with i16 neighbor indices): prefer d_ws; fall back to
  // the local-output region of d_out (16.8 MB). With d_ws, local MLP can be
  // fused into the fps1 launch (it writes d_out directly); without, local
  // must run LAST since scratch aliases its output region.
  const size_t NEED = 7725056;
  bool has_ws = (ws_size >= NEED);
  char* sc = has_ws ? (char*)d_ws : (char*)d_out;
  float* h1   = (float*)(sc + 0);        // 4*2048*128 f32 = 4,194,304 B
  float* h2   = (float*)(sc + 4194304);  // 4*512*256 f32  = 2,097,152 B
  float* c1   = (float*)(sc + 6291456);  // 4*2048*3 f32   =    98,304 B
  float* c2   = (float*)(sc + 6389760);  // 4*512*3 f32    =    24,576 B
  short* nbr1 = (short*)(sc + 6414336);  // 4*2048*64 i16  = 1,048,576 B
  short* nbr2 = (short*)(sc + 7462912);  // 4*512*64 i16   =   262,144 B (end 7,725,056)

  if (has_ws) {
    // fused schedule: fps1 hides local_mlp; fps2 hides nbr1; group1 hides nbr2
    k_fps1_local<<<BB + BB * MM / 8, 512, 0, stream>>>(
        pos, c1, lw0, lb0, lw1, lb1, lw2, lb2, out);
  } else {
    fps1_kernel<<<BB, 512, 0, stream>>>(pos, c1);
  }
  k_fps2_nbr1<<<BB + BB * SS1 / 8, 512, 0, stream>>>(pos, c1, c2, nbr1);
  k_group1_nbr2<<<BB * SS1 + BB * SS2 / 4, 256, 0, stream>>>(
      pos, x, c1, nbr1, g1w0, g1b0, g1w1, g1b1, h1, c2, nbr2);
  group2_kernel<<<BB * SS2, 256, 0, stream>>>(h1, c1, c2, nbr2, g2w0, g2b0, g2w1, g2b1, h2);
  gmax_kernel<<<BB, 256, 0, stream>>>(h2, out);
  if (!has_ws) {
    local_mlp_kernel<<<BB * MM / 8, 512, 0, stream>>>(pos, lw0, lb0, lw1, lb1, lw2, lb2, out);
  }
}

// Round 10
// 3822.229 us; speedup vs baseline: 1.0310x; 1.0145x over previous
//
#include <hip/hip_runtime.h>
#include <hip/hip_bf16.h>

#define BB 4
#define MM 8192
#define SS1 2048
#define SS2 512

using ull = unsigned long long;
typedef float f32x2 __attribute__((ext_vector_type(2)));

// ---------------- packed f32 helpers (VOP3P, per-element IEEE-identical) ----------------
__device__ __forceinline__ f32x2 pk_add(f32x2 a, f32x2 b) {
  f32x2 r; asm("v_pk_add_f32 %0, %1, %2" : "=v"(r) : "v"(a), "v"(b)); return r;
}
__device__ __forceinline__ f32x2 pk_mul(f32x2 a, f32x2 b) {
  f32x2 r; asm("v_pk_mul_f32 %0, %1, %2" : "=v"(r) : "v"(a), "v"(b)); return r;
}

// ---------------- DPP helpers ----------
template <int CTRL>
__device__ __forceinline__ void dpp_max_step(ull& k) {
  unsigned lo = (unsigned)k, hi = (unsigned)(k >> 32);
  unsigned plo = (unsigned)__builtin_amdgcn_update_dpp(0, (int)lo, CTRL, 0xF, 0xF, true);
  unsigned phi = (unsigned)__builtin_amdgcn_update_dpp(0, (int)hi, CTRL, 0xF, 0xF, true);
  ull pk = ((ull)phi << 32) | plo;
  if (pk > k) k = pk;
}

// full-wave max, result in lane 63
__device__ __forceinline__ void wave_max_u64(ull& k) {
  dpp_max_step<0x111>(k);  // row_shr:1
  dpp_max_step<0x112>(k);  // row_shr:2
  dpp_max_step<0x114>(k);  // row_shr:4
  dpp_max_step<0x118>(k);  // row_shr:8
  dpp_max_step<0x142>(k);  // row_bcast:15
  dpp_max_step<0x143>(k);  // row_bcast:31 -> lane63 = wave max
}

// 8-lane max (entries in lanes 0..7), result in lane 7: 3 dependent steps
__device__ __forceinline__ void row8_max_u64(ull& k) {
  dpp_max_step<0x111>(k);
  dpp_max_step<0x112>(k);
  dpp_max_step<0x114>(k);
}

// ---------------- farthest point sampling core (8 waves) ----------------
// Exact f32 numpy semantics: contract-off rounding order preserved exactly
// (pk ops are per-element IEEE-identical; a+(-c) == a-c bitwise). argmax ties
// -> lowest index via key (d2<<32)|~idx. R9 post-mortem: body issue is NOT
// binding (pk halved it, time unchanged); per-iter floor is the serial
// reduce/barrier chain. This core is the best-measured variant (R7 tail).
template <int MP, int NSEL, int THREADS>
__device__ __forceinline__ void fps_core(const float* __restrict__ p,
                                         float* __restrict__ c_out,
                                         char* smem) {
  constexpr int E = MP / THREADS;
  constexpr int P = E / 2;
  constexpr int W = THREADS / 64;
  static_assert(W == 8, "row8 tail assumes exactly 8 waves");
  static_assert(MP % THREADS == 0 && (E % 2) == 0, "geometry");
  float4* sp = (float4*)smem;                                    // 16*MP
  float* cbuf = (float*)(smem + sizeof(float4) * MP);            // 12*NSEL
  ull* kb = (ull*)(smem + sizeof(float4) * MP + sizeof(float) * NSEL * 3);  // 2*W*8
  int t = threadIdx.x;
  int lane = t & 63, wv = t >> 6;
  for (int i = t; i < MP; i += THREADS)
    sp[i] = make_float4(p[i * 3 + 0], p[i * 3 + 1], p[i * 3 + 2], 0.f);
  __syncthreads();
  // register-resident points as packed pairs (elems 2p and 2p+1) + running dd
  f32x2 X[P], Y[P], Z[P], D[P];
  #pragma unroll
  for (int pp = 0; pp < P; ++pp) {
    float4 qa = sp[t + (2 * pp + 0) * THREADS];  // conflict-free ds_read_b128
    float4 qb = sp[t + (2 * pp + 1) * THREADS];
    X[pp] = (f32x2){qa.x, qb.x};
    Y[pp] = (f32x2){qa.y, qb.y};
    Z[pp] = (f32x2){qa.z, qb.z};
    D[pp] = (f32x2){INFINITY, INFINITY};
  }
  float4 c0 = sp[0];
  float cx = c0.x, cy = c0.y, cz = c0.z;
  if (t == 0) { cbuf[0] = cx; cbuf[1] = cy; cbuf[2] = cz; }
  int par = 0;
  for (int it = 1; it < NSEL; ++it) {
    float bd = -1.0f;
    int be = 0;
    float ncx = -cx, ncy = -cy, ncz = -cz;  // a+(-c) == a-c bit-exactly
    f32x2 NX = (f32x2){ncx, ncx}, NY = (f32x2){ncy, ncy}, NZ = (f32x2){ncz, ncz};
    #pragma unroll
    for (int pp = 0; pp < P; ++pp) {
      f32x2 dx = pk_add(X[pp], NX);
      f32x2 dy = pk_add(Y[pp], NY);
      f32x2 dz = pk_add(Z[pp], NZ);
      f32x2 sx = pk_mul(dx, dx);
      f32x2 sy = pk_mul(dy, dy);
      f32x2 s1 = pk_add(sx, sy);
      f32x2 sz = pk_mul(dz, dz);
      f32x2 nd = pk_add(s1, sz);
      float d0 = fminf(D[pp].x, nd.x);
      float d1 = fminf(D[pp].y, nd.y);
      D[pp].x = d0;
      D[pp].y = d1;
      if (d0 > bd) { bd = d0; be = 2 * pp; }      // ascending e, strict >:
      if (d1 > bd) { bd = d1; be = 2 * pp + 1; }  // lowest e kept (lowest idx)
    }
    int bidx = t + be * THREADS;  // idx monotone in e -> in-thread ties exact
    ull k = ((ull)__float_as_uint(bd) << 32) | (unsigned)(~bidx);
    wave_max_u64(k);
    if (lane == 63) kb[par * W + wv] = k;
    __syncthreads();
    ull v = 0;
    if (lane < W) v = kb[par * W + lane];  // one predicated ds_read_b64 per wave
    row8_max_u64(v);                       // lane7 = block max (W==8)
    unsigned glo = __builtin_amdgcn_readlane((unsigned)v, 7);  // low word: ~bidx
    int widx = (int)(~glo) & (MP - 1);  // mask: replay-safe no-op
    float4 cw = sp[widx];  // uniform address -> LDS broadcast
    cx = cw.x; cy = cw.y; cz = cw.z;
    if (t == 0) {
      cbuf[it * 3 + 0] = cx;
      cbuf[it * 3 + 1] = cy;
      cbuf[it * 3 + 2] = cz;
    }
    par ^= 1;
  }
  __syncthreads();
  for (int i = t; i < NSEL * 3; i += THREADS) c_out[i] = cbuf[i];
}

// ---------------- ball query core: 64 nearest with d2 <= R2, ties by lower index ----------------
// One wave per center, NW waves per block. Output indices i16 (-1..8191 lossless).
template <int MP, int NW>
__device__ __forceinline__ void nbr_core(const float* __restrict__ pts,
                                         const float* __restrict__ cen, int S,
                                         float R2, short* __restrict__ nbr,
                                         ull* buf, int blk) {
  constexpr int CAP = 1024;
  int t = threadIdx.x;
  int wv = t >> 6, lane = t & 63;
  int gw = blk * NW + wv;
  int b = gw / S, s = gw % S;
  const float* p = pts + (size_t)b * MP * 3;
  const float* c = cen + ((size_t)b * S + s) * 3;
  float cx = c[0], cy = c[1], cz = c[2];
  ull* bw = buf + (size_t)wv * CAP;
  int cnt = 0;
  {
    #pragma clang fp contract(off)
    for (int i0 = 0; i0 < MP; i0 += 64) {
      int i = i0 + lane;
      float dx = p[i * 3 + 0] - cx;
      float dy = p[i * 3 + 1] - cy;
      float dz = p[i * 3 + 2] - cz;
      float d2 = dx * dx;
      d2 += dy * dy;
      d2 += dz * dz;
      bool in = (d2 <= R2);
      ull mask = __ballot(in);
      if (in) {
        int off = __popcll(mask & ((1ull << lane) - 1ull));
        int pos = cnt + off;
        if (pos < CAP)
          bw[pos] = ((ull)__float_as_uint(d2) << 32) | (unsigned)i;
      }
      cnt += __popcll(mask);
    }
  }
  if (cnt > CAP) cnt = CAP;
  __syncthreads();  // uniform within this path; ensures LDS writes visible
  int out = -1;
  if (cnt <= 64) {
    if (lane < cnt) out = (int)(unsigned)bw[lane];
  } else {
    for (int r = 0; r < 64; ++r) {
      ull mk = ~0ull;
      int mj = -1;
      for (int j = lane; j < cnt; j += 64) {
        ull v = bw[j];
        if (v < mk) { mk = v; mj = j; }
      }
      ull kc = ~mk;
      wave_max_u64(kc);
      ull g = ~__shfl(kc, 63, 64);
      if (mk == g && mj >= 0) bw[mj] = ~0ull;  // unique keys -> exactly one owner
      asm volatile("s_waitcnt lgkmcnt(0)" ::: "memory");
      if (lane == r) out = (int)(unsigned)g;
    }
  }
  nbr[((size_t)b * S + s) * 64 + lane] = (short)out;
}

// ---------------- K_A: fps1 (blocks 0..3) U local MLP (blocks 4..4+BB*MM/8) ----------------
// local branch: pos -> 64 -> 64 -> 128 (tanh each), 8 points per 512-thread block.
__global__ __launch_bounds__(512) void k_fps1_local(
    const float* __restrict__ pos, float* __restrict__ c1,
    const float* __restrict__ w0, const float* __restrict__ b0,
    const float* __restrict__ w1, const float* __restrict__ b1,
    const float* __restrict__ w2, const float* __restrict__ b2,
    float* __restrict__ out) {
  __shared__ __align__(16) char smem[16 * MM + 12 * SS1 + 128];  // 155,776 B
  if (blockIdx.x < BB) {
    int b = blockIdx.x;
    fps_core<MM, SS1, 512>(pos + (size_t)b * MM * 3, c1 + (size_t)b * SS1 * 3, smem);
  } else {
    float* p  = (float*)smem;           // [8][3]
    float* h0 = (float*)smem + 32;      // [8][64]
    float* h1 = (float*)smem + 32 + 512;// [8][64]
    int t = threadIdx.x;
    size_t pid0 = (size_t)(blockIdx.x - BB) * 8;
    if (t < 24) {
      int pp = t / 3, j = t % 3;
      p[pp * 3 + j] = pos[(pid0 + pp) * 3 + j];
    }
    __syncthreads();
    {
      int pp = t >> 6, c = t & 63;
      float acc = b0[c];
      #pragma unroll
      for (int j = 0; j < 3; ++j) acc += p[pp * 3 + j] * w0[j * 64 + c];
      h0[pp * 64 + c] = tanhf(acc);
    }
    __syncthreads();
    {
      int pp = t >> 6, c = t & 63;
      float acc = b1[c];
      #pragma unroll
      for (int j = 0; j < 64; ++j) acc += h0[pp * 64 + j] * w1[j * 64 + c];
      h1[pp * 64 + c] = tanhf(acc);
    }
    __syncthreads();
    #pragma unroll
    for (int r = 0; r < 2; ++r) {
      int o = t + 512 * r;
      int pp = o >> 7, c = o & 127;
      float acc = b2[c];
      #pragma unroll
      for (int j = 0; j < 64; ++j) acc += h1[pp * 64 + j] * w2[j * 128 + c];
      out[(pid0 + pp) * 128 + c] = tanhf(acc);
    }
  }
}

// standalone fps1 (fallback path when scratch aliases d_out: local must run LAST)
__global__ __launch_bounds__(512, 1) void fps1_kernel(const float* __restrict__ pts,
                                                      float* __restrict__ cen) {
  __shared__ __align__(16) char smem[16 * MM + 12 * SS1 + 128];
  fps_core<MM, SS1, 512>(pts + (size_t)blockIdx.x * MM * 3,
                         cen + (size_t)blockIdx.x * SS1 * 3, smem);
}

// standalone local MLP (fallback path), 8 pts per 512-thread block
__global__ __launch_bounds__(512) void local_mlp_kernel(
    const float* __restrict__ pos,
    const float* __restrict__ w0, const float* __restrict__ b0,
    const float* __restrict__ w1, const float* __restrict__ b1,
    const float* __restrict__ w2, const float* __restrict__ b2,
    float* __restrict__ out) {
  __shared__ float p[8][3];
  __shared__ float h0[8][64];
  __shared__ float h1[8][64];
  int t = threadIdx.x;
  size_t pid0 = (size_t)blockIdx.x * 8;
  if (t < 24) {
    int pp = t / 3, j = t % 3;
    p[pp][j] = pos[(pid0 + pp) * 3 + j];
  }
  __syncthreads();
  {
    int pp = t >> 6, c = t & 63;
    float acc = b0[c];
    #pragma unroll
    for (int j = 0; j < 3; ++j) acc += p[pp][j] * w0[j * 64 + c];
    h0[pp][c] = tanhf(acc);
  }
  __syncthreads();
  {
    int pp = t >> 6, c = t & 63;
    float acc = b1[c];
    #pragma unroll
    for (int j = 0; j < 64; ++j) acc += h0[pp][j] * w1[j * 64 + c];
    h1[pp][c] = tanhf(acc);
  }
  __syncthreads();
  #pragma unroll
  for (int r = 0; r < 2; ++r) {
    int o = t + 512 * r;
    int pp = o >> 7, c = o & 127;
    float acc = b2[c];
    #pragma unroll
    for (int j = 0; j < 64; ++j) acc += h1[pp][j] * w2[j * 128 + c];
    out[(pid0 + pp) * 128 + c] = tanhf(acc);
  }
}

// ---------------- K_B: fps2 8-wave (blocks 0..3) U nbr1 (blocks 4..) ----------------
// 64KB smem -> 2 blocks/CU (R6 config): best measured rest-chain (1792us vs
// 1834us with the R8 96KB "isolation" -- starving nbr1 to 1 block/CU cost
// more than fps2 sharing a CU with one nbr block costs).
__global__ __launch_bounds__(512) void k_fps2_nbr1(
    const float* __restrict__ pos, const float* __restrict__ c1,
    float* __restrict__ c2, short* __restrict__ nbr1) {
  __shared__ __align__(16) char smem[8 * 1024 * 8];  // 64 KB (nbr) >= 39 KB (fps2)
  if (blockIdx.x < BB) {
    int b = blockIdx.x;
    fps_core<SS1, SS2, 512>(c1 + (size_t)b * SS1 * 3, c2 + (size_t)b * SS2 * 3, smem);
  } else {
    nbr_core<MM, 8>(pos, c1, SS1, 0.04f, nbr1, (ull*)smem, blockIdx.x - BB);
  }
}

// ---------------- K_C: group1 (blocks 0..BB*SS1) U nbr2 (tail blocks) ----------------
// SA1 grouped MLP: feats[64][9] -> 64 -> 128, masked PRE-ACT max over K;
// layer2 register-tiled 8k x 4ch; tanh/bias deferred past the masked max (exact).
// R21: layer2 j-loop unroll 2 -> 4 global weight loads in flight (was 2);
// R5 PMC showed VALUBusy 17.5% = vmcnt-stall-bound, not issue-bound.
__global__ __launch_bounds__(256, 4) void k_group1_nbr2(
    const float* __restrict__ pos, const float* __restrict__ x,
    const float* __restrict__ c1, const short* __restrict__ nbr,
    const float* __restrict__ w0, const float* __restrict__ b0,
    const float* __restrict__ w1, const float* __restrict__ b1,
    float* __restrict__ h1out,
    const float* __restrict__ c2, short* __restrict__ nbr2out) {
  __shared__ __align__(16) char smem[32768];  // nbr2 32KB >= group1 ~24.9KB
  if (blockIdx.x >= BB * SS1) {
    nbr_core<SS1, 4>(c1, c2, SS2, 0.16f, nbr2out, (ull*)smem, blockIdx.x - BB * SS1);
    return;
  }
  float (*feats)[12] = (float(*)[12])smem;                    // 3072 B
  float (*hbuf)[68]  = (float(*)[68])(smem + 3072);           // 17408 B
  float (*Mred)[128] = (float(*)[128])(smem + 3072 + 17408);  // 4096 B
  int* nb            = (int*)(smem + 3072 + 17408 + 4096);    // 256 B
  float* cc          = (float*)(smem + 3072 + 17408 + 4096 + 256);  // 12 B
  int t = threadIdx.x;
  int bs = blockIdx.x;  // b*S1 + s
  int b = bs >> 11;
  if (t < 64) nb[t] = (int)nbr[(size_t)bs * 64 + t];
  if (t < 3) cc[t] = c1[(size_t)bs * 3 + t];
  __syncthreads();
  if (t < 64) {
    int n = nb[t];
    int ni = ((unsigned)n < (unsigned)MM) ? n : 0;  // clamp: replay-safe
    const float* pp = pos + ((size_t)b * MM + ni) * 3;
    const float* xx = x + ((size_t)b * MM + ni) * 3;
    float p0 = pp[0], p1 = pp[1], p2 = pp[2];
    feats[t][0] = p0; feats[t][1] = p1; feats[t][2] = p2;
    feats[t][3] = xx[0]; feats[t][4] = xx[1]; feats[t][5] = xx[2];
    feats[t][6] = p0 - cc[0]; feats[t][7] = p1 - cc[1]; feats[t][8] = p2 - cc[2];
  }
  __syncthreads();
  // layer1: 9 -> 64; thread (k = t>>2, q = t&3) computes 16 channels
  {
    int k = t >> 2, q = t & 3;
    float acc[16];
    #pragma unroll
    for (int i = 0; i < 16; ++i) acc[i] = b0[q * 16 + i];
    #pragma unroll
    for (int j = 0; j < 9; ++j) {
      float f = feats[k][j];
      const float4* wr = (const float4*)(w0 + j * 64 + q * 16);
      #pragma unroll
      for (int i = 0; i < 4; ++i) {
        float4 wvv = wr[i];
        acc[4 * i + 0] += f * wvv.x;
        acc[4 * i + 1] += f * wvv.y;
        acc[4 * i + 2] += f * wvv.z;
        acc[4 * i + 3] += f * wvv.w;
      }
    }
    #pragma unroll
    for (int i = 0; i < 16; ++i) hbuf[k][q * 16 + i] = tanhf(acc[i]);
  }
  __syncthreads();
  // layer2: hidden[64][64] x W1[64][128], masked PRE-ACT max over k
  {
    int kt = t >> 5;  // 0..7
    int ct = t & 31;  // 0..31
    float acc[8][4];
    #pragma unroll
    for (int a = 0; a < 8; ++a)
      #pragma unroll
      for (int ci = 0; ci < 4; ++ci) acc[a][ci] = 0.f;
    const float* wbase = w1 + ct * 4;
    #pragma unroll 2
    for (int j = 0; j < 64; j += 2) {
      float2 fv[8];
      #pragma unroll
      for (int kk = 0; kk < 8; ++kk)
        fv[kk] = *(const float2*)&hbuf[kt * 8 + kk][j];
      float wja[4], wjb[4];
      *(float4*)&wja[0] = *(const float4*)(wbase + (size_t)j * 128);
      *(float4*)&wjb[0] = *(const float4*)(wbase + (size_t)(j + 1) * 128);
      #pragma unroll
      for (int kk = 0; kk < 8; ++kk)
        #pragma unroll
        for (int ci = 0; ci < 4; ++ci) {
          acc[kk][ci] += fv[kk].x * wja[ci];
          acc[kk][ci] += fv[kk].y * wjb[ci];
        }
    }
    float m[4];
    #pragma unroll
    for (int ci = 0; ci < 4; ++ci) m[ci] = -INFINITY;
    #pragma unroll
    for (int kk = 0; kk < 8; ++kk) {
      if (nb[kt * 8 + kk] >= 0) {
        #pragma unroll
        for (int ci = 0; ci < 4; ++ci) m[ci] = fmaxf(m[ci], acc[kk][ci]);
      }
    }
    #pragma unroll
    for (int ci = 0; ci < 4; ++ci) Mred[kt][ct * 4 + ci] = m[ci];
  }
  __syncthreads();
  if (t < 128) {
    float mxv = Mred[0][t];
    #pragma unroll
    for (int r = 1; r < 8; ++r) mxv = fmaxf(mxv, Mred[r][t]);
    h1out[(size_t)bs * 128 + t] = tanhf(mxv + b1[t]);  // bias+tanh after max: exact
  }
}

// ---------------- SA2 grouped MLP: feats[64][131] -> 128 -> 256, masked max over K ----------------
// R21: layer1/layer2 loops unroll 2 (more weight loads in flight; vmcnt-stall fix).
__global__ __launch_bounds__(256, 4) void group2_kernel(
    const float* __restrict__ h1, const float* __restrict__ c1,
    const float* __restrict__ c2, const short* __restrict__ nbr,
    const float* __restrict__ w0, const float* __restrict__ b0,
    const float* __restrict__ w1, const float* __restrict__ b1,
    float* __restrict__ h2out) {
  __shared__ float fb[64][132];  // feats (131) then reused as hidden (128)
  __shared__ float Mred[8][256];
  __shared__ int nb[64];
  __shared__ float cc[3];
  int t = threadIdx.x;
  int bs = blockIdx.x;  // b*S2 + s
  int b = bs >> 9;
  if (t < 64) nb[t] = (int)nbr[(size_t)bs * 64 + t];
  if (t < 3) cc[t] = c2[(size_t)bs * 3 + t];
  __syncthreads();
  {
    int k = t >> 2, q = t & 3;
    int n = nb[k];
    int ni = ((unsigned)n < (unsigned)SS1) ? n : 0;  // clamp: replay-safe
    const float* hrow = h1 + ((size_t)b * SS1 + ni) * 128;
    #pragma unroll
    for (int i = 0; i < 32; ++i) fb[k][q * 32 + i] = hrow[q * 32 + i];
    if (q == 0) {
      const float* pr = c1 + ((size_t)b * SS1 + ni) * 3;
      fb[k][128] = pr[0] - cc[0];
      fb[k][129] = pr[1] - cc[1];
      fb[k][130] = pr[2] - cc[2];
    }
  }
  __syncthreads();
  float acc1[32];
  {
    int k = t >> 2, q = t & 3;
    #pragma unroll
    for (int i = 0; i < 32; ++i) acc1[i] = b0[q * 32 + i];
    #pragma unroll 2
    for (int j = 0; j < 131; ++j) {
      float f = fb[k][j];
      const float4* wr = (const float4*)(w0 + (size_t)j * 128 + q * 32);
      #pragma unroll
      for (int i = 0; i < 8; ++i) {
        float4 wvv = wr[i];
        acc1[4 * i + 0] += f * wvv.x;
        acc1[4 * i + 1] += f * wvv.y;
        acc1[4 * i + 2] += f * wvv.z;
        acc1[4 * i + 3] += f * wvv.w;
      }
    }
  }
  __syncthreads();
  {
    int k = t >> 2, q = t & 3;
    #pragma unroll
    for (int i = 0; i < 32; ++i) fb[k][q * 32 + i] = tanhf(acc1[i]);
  }
  __syncthreads();
  {
    int kt = t >> 5;  // 0..7
    int ct = t & 31;  // 0..31
    float acc[8][8];
    #pragma unroll
    for (int a = 0; a < 8; ++a)
      #pragma unroll
      for (int c2i = 0; c2i < 8; ++c2i) acc[a][c2i] = 0.f;
    const float* wbase = w1 + ct * 8;
    #pragma unroll 2
    for (int j = 0; j < 128; j += 2) {
      float2 fv[8];
      #pragma unroll
      for (int kk = 0; kk < 8; ++kk)
        fv[kk] = *(const float2*)&fb[kt * 8 + kk][j];
      float wja[8], wjb[8];
      const float4* wp0 = (const float4*)(wbase + (size_t)j * 256);
      const float4* wp1 = (const float4*)(wbase + (size_t)(j + 1) * 256);
      *(float4*)&wja[0] = wp0[0];
      *(float4*)&wja[4] = wp0[1];
      *(float4*)&wjb[0] = wp1[0];
      *(float4*)&wjb[4] = wp1[1];
      #pragma unroll
      for (int kk = 0; kk < 8; ++kk)
        #pragma unroll
        for (int ci = 0; ci < 8; ++ci) {
          acc[kk][ci] += fv[kk].x * wja[ci];
          acc[kk][ci] += fv[kk].y * wjb[ci];
        }
    }
    float m[8];
    #pragma unroll
    for (int ci = 0; ci < 8; ++ci) m[ci] = -INFINITY;
    #pragma unroll
    for (int kk = 0; kk < 8; ++kk) {
      if (nb[kt * 8 + kk] >= 0) {
        #pragma unroll
        for (int ci = 0; ci < 8; ++ci) m[ci] = fmaxf(m[ci], acc[kk][ci]);
      }
    }
    #pragma unroll
    for (int ci = 0; ci < 8; ++ci) Mred[kt][ct * 8 + ci] = m[ci];
  }
  __syncthreads();
  if (t < 256) {
    float mxv = Mred[0][t];
    #pragma unroll
    for (int r = 1; r < 8; ++r) mxv = fmaxf(mxv, Mred[r][t]);
    h2out[(size_t)bs * 256 + t] = tanhf(mxv + b1[t]);  // bias+tanh after max: exact
  }
}

// ---------------- global max over centers ----------------
__global__ __launch_bounds__(256) void gmax_kernel(const float* __restrict__ h2,
                                                   float* __restrict__ out) {
  int b = blockIdx.x, c = threadIdx.x;
  float mx = -INFINITY;
  for (int s = 0; s < SS2; ++s)
    mx = fmaxf(mx, h2[((size_t)b * SS2 + s) * 256 + c]);
  out[(size_t)BB * MM * 128 + b * 256 + c] = mx;
}

extern "C" void kernel_launch(void* const* d_in, const int* in_sizes, int n_in,
                              void* d_out, int out_size, void* d_ws, size_t ws_size,
                              hipStream_t stream) {
  // Reference is pure float32: all inputs AND the output buffer are f32.
  const float* x    = (const float*)d_in[0];
  const float* pos  = (const float*)d_in[1];
  const float* lw0  = (const float*)d_in[2];
  const float* lb0  = (const float*)d_in[3];
  const float* lw1  = (const float*)d_in[4];
  const float* lb1  = (const float*)d_in[5];
  const float* lw2  = (const float*)d_in[6];
  const float* lb2  = (const float*)d_in[7];
  const float* g1w0 = (const float*)d_in[8];
  const float* g1b0 = (const float*)d_in[9];
  const float* g1w1 = (const float*)d_in[10];
  const float* g1b1 = (const float*)d_in[11];
  const float* g2w0 = (const float*)d_in[12];
  const float* g2b0 = (const float*)d_in[13];
  const float* g2w1 = (const float*)d_in[14];
  const float* g2b1 = (const float*)d_in[15];
  float* out = (float*)d_out;

  // Scratch (7.73 MB with i16 neighbor indices): prefer d_ws; fall back to
  // the local-output region of d_out (16.8 MB). With d_ws, local MLP can be
  // fused into the fps1 launch (it writes d_out directly); without, local
  // must run LAST since scratch aliases its output region.
  const size_t NEED = 7725056;
  bool has_ws = (ws_size >= NEED);
  char* sc = has_ws ? (char*)d_ws : (char*)d_out;
  float* h1   = (float*)(sc + 0);        // 4*2048*128 f32 = 4,194,304 B
  float* h2   = (float*)(sc + 4194304);  // 4*512*256 f32  = 2,097,152 B
  float* c1   = (float*)(sc + 6291456);  // 4*2048*3 f32   =    98,304 B
  float* c2   = (float*)(sc + 6389760);  // 4*512*3 f32    =    24,576 B
  short* nbr1 = (short*)(sc + 6414336);  // 4*2048*64 i16  = 1,048,576 B
  short* nbr2 = (short*)(sc + 7462912);  // 4*512*64 i16   =   262,144 B (end 7,725,056)

  if (has_ws) {
    // fused schedule: fps1 hides local_mlp; fps2 hides nbr1; group1 hides nbr2
    k_fps1_local<<<BB + BB * MM / 8, 512, 0, stream>>>(
        pos, c1, lw0, lb0, lw1, lb1, lw2, lb2, out);
  } else {
    fps1_kernel<<<BB, 512, 0, stream>>>(pos, c1);
  }
  k_fps2_nbr1<<<BB + BB * SS1 / 8, 512, 0, stream>>>(pos, c1, c2, nbr1);
  k_group1_nbr2<<<BB * SS1 + BB * SS2 / 4, 256, 0, stream>>>(
      pos, x, c1, nbr1, g1w0, g1b0, g1w1, g1b1, h1, c2, nbr2);
  group2_kernel<<<BB * SS2, 256, 0, stream>>>(h1, c1, c2, nbr2, g2w0, g2b0, g2w1, g2b1, h2);
  gmax_kernel<<<BB, 256, 0, stream>>>(h2, out);
  if (!has_ws) {
    local_mlp_kernel<<<BB * MM / 8, 512, 0, stream>>>(pos, lw0, lb0, lw1, lb1, lw2, lb2, out);
  }
}